// Round 1
// baseline (572.188 us; speedup 1.0000x reference)
//
#include <hip/hip_runtime.h>
#include <math.h>

// dims
#define HWHW 2304   // 48*48
#define JD   144    // 12*12
#define NBG  8      // b*G

// ws layout (float offsets)
// q    [8][32][2304]   @ 0
// qt   [8][2304][32]   @ 589824
// vn0  [8][144]        @ 1179648
// vn1  [8][144]        @ 1180800
// px   [8][144]        @ 1181952
// py   [8][144]        @ 1183104
// kt   [8][144][32]    @ 1184256
// vt   [8][144][32]    @ 1221120
// outh [2][2304][128]  @ 1257984
// L    [8][2304][144]  @ 1847808   (end 4502016 floats = 18.0 MB)

__global__ __launch_bounds__(256) void qproj_kernel(
    const float* __restrict__ x, const float* __restrict__ wq,
    float* __restrict__ q, float* __restrict__ qt) {
  int hw = blockIdx.x * 256 + threadIdx.x;
  int o = blockIdx.y, bg = blockIdx.z;
  int b = bg >> 2, g = bg & 3;
  const float* wrow = wq + (g * 32 + o) * 32;   // uniform -> scalar loads
  const float* xp = x + (b * 128 + g * 32) * HWHW + hw;
  float acc = 0.f;
#pragma unroll
  for (int c = 0; c < 32; ++c) acc += wrow[c] * xp[c * HWHW];
  q[(bg * 32 + o) * HWHW + hw] = acc;
  qt[(bg * HWHW + hw) * 32 + o] = acc;
}

__global__ __launch_bounds__(192) void offset_kernel(
    const float* __restrict__ q, const float* __restrict__ wdw,
    const float* __restrict__ bdw, const float* __restrict__ wproj,
    float* __restrict__ vn0, float* __restrict__ vn1,
    float* __restrict__ px, float* __restrict__ py) {
  int t = threadIdx.x;
  int bg = blockIdx.x;
  if (t >= JD) return;
  int hd = t / 12, wd = t - (t / 12) * 12;
  float a0 = 0.f, a1 = 0.f;
  for (int c = 0; c < 32; ++c) {
    const float* qp = q + (bg * 32 + c) * HWHW;
    const float* wp = wdw + c * 36;             // uniform -> scalar
    float s = 0.f;
#pragma unroll
    for (int ky = 0; ky < 6; ++ky) {
      int hy = hd * 4 - 1 + ky;
      if (hy < 0 || hy >= 48) continue;
#pragma unroll
      for (int kx = 0; kx < 6; ++kx) {
        int wx = wd * 4 - 1 + kx;
        if (wx < 0 || wx >= 48) continue;
        s += wp[ky * 6 + kx] * qp[hy * 48 + wx];
      }
    }
    s += bdw[c];
    s = 0.5f * s * (1.f + erff(s * 0.70710678118654752f));  // exact GELU
    a0 += wproj[c] * s;
    a1 += wproj[32 + c] * s;
  }
  float off0 = tanhf(a0) * 4.f;
  float off1 = tanhf(a1) * 4.f;
  float n0 = 2.f * ((float)wd + off0) / 11.f - 1.f;
  float n1 = 2.f * ((float)hd + off1) / 11.f - 1.f;
  vn0[bg * JD + t] = n0;
  vn1[bg * JD + t] = n1;
  px[bg * JD + t] = ((n0 + 1.f) * 48.f - 1.f) * 0.5f;
  py[bg * JD + t] = ((n1 + 1.f) * 48.f - 1.f) * 0.5f;
}

__global__ __launch_bounds__(256) void kv_kernel(
    const float* __restrict__ x, const float* __restrict__ wk,
    const float* __restrict__ wv, const float* __restrict__ px,
    const float* __restrict__ py, float* __restrict__ kt,
    float* __restrict__ vt) {
  __shared__ float kv[32][JD];
  __shared__ float wkl[32][33], wvl[32][33];
  int bg = blockIdx.x, b = bg >> 2, g = bg & 3;
  int t = threadIdx.x;
  for (int u = t; u < 1024; u += 256) {
    int d = u >> 5, c = u & 31;
    wkl[d][c] = wk[g * 1024 + u];
    wvl[d][c] = wv[g * 1024 + u];
  }
  for (int u = t; u < 32 * JD; u += 256) {
    int c = u / JD, j = u - c * JD;
    float fx = px[bg * JD + j], fy = py[bg * JD + j];
    float x0 = floorf(fx), y0 = floorf(fy);
    float wx = fx - x0, wy = fy - y0;
    int xi = (int)x0, yi = (int)y0;
    const float* xp = x + (b * 128 + g * 32 + c) * HWHW;
    float v00 = 0.f, v10 = 0.f, v01 = 0.f, v11 = 0.f;
    bool okx0 = (xi >= 0) & (xi < 48), okx1 = (xi + 1 >= 0) & (xi + 1 < 48);
    if (yi >= 0 && yi < 48) {
      if (okx0) v00 = xp[yi * 48 + xi];
      if (okx1) v10 = xp[yi * 48 + xi + 1];
    }
    if (yi + 1 >= 0 && yi + 1 < 48) {
      if (okx0) v01 = xp[(yi + 1) * 48 + xi];
      if (okx1) v11 = xp[(yi + 1) * 48 + xi + 1];
    }
    kv[c][j] = v00 * (1.f - wx) * (1.f - wy) + v10 * wx * (1.f - wy)
             + v01 * (1.f - wx) * wy + v11 * wx * wy;
  }
  __syncthreads();
  for (int u = t; u < 32 * JD; u += 256) {
    int j = u >> 5, d = u & 31;
    float ak = 0.f, av = 0.f;
#pragma unroll
    for (int c = 0; c < 32; ++c) {
      float val = kv[c][j];
      ak += wkl[d][c] * val;
      av += wvl[d][c] * val;
    }
    kt[bg * 4608 + u] = ak;  // [j][d]
    vt[bg * 4608 + u] = av;
  }
}

__global__ __launch_bounds__(256) void logits_kernel(
    const float* __restrict__ qt, const float* __restrict__ kt,
    const float* __restrict__ vn0, const float* __restrict__ vn1,
    const float* __restrict__ w0, const float* __restrict__ b0,
    const float* __restrict__ w1, const float* __restrict__ b1,
    const float* __restrict__ w2, const float* __restrict__ b2,
    float* __restrict__ L) {
  __shared__ float skT[32][JD];   // [d][j] transposed: j-lane reads conflict-free
  __shared__ float sq[16][32];
  __shared__ float sv0[JD], sv1[JD];
  int bg = blockIdx.y;
  int i0 = blockIdx.x * 16;
  int t = threadIdx.x;
  for (int u = t; u < 4608; u += 256) {
    int j = u >> 5, d = u & 31;
    skT[d][j] = kt[bg * 4608 + u];
  }
  for (int u = t; u < 512; u += 256) sq[u >> 5][u & 31] = qt[(bg * HWHW + i0) * 32 + u];
  if (t < JD) { sv0[t] = vn0[bg * JD + t]; sv1[t] = vn1[bg * JD + t]; }
  __syncthreads();
  const float scale = 0.17677669529663687f;  // 32^-0.5
  float bias2 = b2[0];
#pragma unroll 1
  for (int pp = 0; pp < 9; ++pp) {
    int p = pp * 256 + t;
    int ii = p / JD;
    int jj = p - ii * JD;
    int i = i0 + ii;
    int iy = i / 48, ix = i - iy * 48;
    float qn0 = (float)ix * (2.f / 47.f) - 1.f;
    float qn1 = (float)iy * (2.f / 47.f) - 1.f;
    float p0 = qn0 - sv0[jj];
    float p1 = qn1 - sv1[jj];
    float s0 = copysignf(log1pf(fabsf(p0)), p0);
    float s1 = copysignf(log1pf(fabsf(p1)), p1);
    float h1[32];
#pragma unroll
    for (int o = 0; o < 32; ++o)
      h1[o] = fmaxf(s0 * w0[o] + s1 * w0[32 + o] + b0[o], 0.f);  // w0/b0 scalar
    float h2[32];
#pragma unroll
    for (int o = 0; o < 32; ++o) h2[o] = b1[o];
#pragma unroll
    for (int c = 0; c < 32; ++c) {
      float hc = h1[c];
#pragma unroll
      for (int o = 0; o < 32; ++o) h2[o] += hc * w1[c * 32 + o];  // s_load + v_fmac(s,v)
    }
    float bias = bias2;
#pragma unroll
    for (int o = 0; o < 32; ++o) bias += fmaxf(h2[o], 0.f) * w2[o];
    float dot = 0.f;
#pragma unroll
    for (int d = 0; d < 32; ++d) dot += sq[ii][d] * skT[d][jj];
    L[(bg * HWHW + i) * JD + jj] = dot * scale + bias;
  }
}

__global__ __launch_bounds__(256) void softmax_pv_kernel(
    const float* __restrict__ L, const float* __restrict__ vt,
    float* __restrict__ outh) {
  __shared__ float vl[JD][32];
  __shared__ float pl[4][JD];
  int bg = blockIdx.y, b = bg >> 2, g = bg & 3;
  int i0 = blockIdx.x * 16;
  int t = threadIdx.x;
  int wid = t >> 6, lane = t & 63;
  for (int u = t; u < 4608; u += 256) vl[u >> 5][u & 31] = vt[bg * 4608 + u];
  __syncthreads();
#pragma unroll 1
  for (int qq = 0; qq < 4; ++qq) {
    int i = i0 + wid * 4 + qq;
    const float* Lp = L + (bg * HWHW + i) * JD;
    float l0 = Lp[lane];
    float l1 = Lp[lane + 64];
    float l2 = (lane < 16) ? Lp[lane + 128] : -INFINITY;
    float m = fmaxf(fmaxf(l0, l1), l2);
#pragma unroll
    for (int s = 32; s >= 1; s >>= 1) m = fmaxf(m, __shfl_xor(m, s, 64));
    float e0 = __expf(l0 - m), e1 = __expf(l1 - m);
    float e2 = (lane < 16) ? __expf(l2 - m) : 0.f;
    float sum = e0 + e1 + e2;
#pragma unroll
    for (int s = 32; s >= 1; s >>= 1) sum += __shfl_xor(sum, s, 64);
    float inv = 1.f / sum;
    pl[wid][lane] = e0 * inv;
    pl[wid][lane + 64] = e1 * inv;
    if (lane < 16) pl[wid][lane + 128] = e2 * inv;
    __syncthreads();
    int d = lane & 31, half = lane >> 5;
    float acc = 0.f;
#pragma unroll
    for (int jj = 0; jj < 72; ++jj) {
      int j = half * 72 + jj;
      acc += pl[wid][j] * vl[j][d];
    }
    acc += __shfl_xor(acc, 32, 64);
    if (lane < 32) outh[(b * HWHW + i) * 128 + g * 32 + d] = acc;
    __syncthreads();
  }
}

__global__ __launch_bounds__(256) void out_kernel(
    const float* __restrict__ outh, const float* __restrict__ wo,
    const float* __restrict__ bo, const float* __restrict__ x,
    const float* __restrict__ gamma, float* __restrict__ out) {
  __shared__ float tile[64 * 129];   // +1 pad: row-read bank-conflict-free
  int b = blockIdx.y;
  int hw0 = blockIdx.x * 64;
  int t = threadIdx.x;
  int wid = t >> 6, lane = t & 63;
  for (int u = t; u < 2048; u += 256) {
    int r = u >> 5, c4 = (u & 31) * 4;
    const float4 v = *(const float4*)(outh + (b * HWHW + hw0 + r) * 128 + c4);
    float* dst = tile + r * 129 + c4;
    dst[0] = v.x; dst[1] = v.y; dst[2] = v.z; dst[3] = v.w;
  }
  __syncthreads();
  float acc[32];
#pragma unroll
  for (int o = 0; o < 32; ++o) acc[o] = 0.f;
  const float* wop = wo + wid * 32 * 128;   // uniform per wave -> scalar
  const float* row = tile + lane * 129;
#pragma unroll 1
  for (int c4 = 0; c4 < 128; c4 += 4) {
    float v0 = row[c4], v1 = row[c4 + 1], v2 = row[c4 + 2], v3 = row[c4 + 3];
#pragma unroll
    for (int o = 0; o < 32; ++o) {
      acc[o] += wop[o * 128 + c4] * v0 + wop[o * 128 + c4 + 1] * v1
              + wop[o * 128 + c4 + 2] * v2 + wop[o * 128 + c4 + 3] * v3;
    }
  }
  float gm = gamma[0];
  float* out0 = out;
  float* out1 = out + 2 * 128 * HWHW;
#pragma unroll
  for (int o = 0; o < 32; ++o) {
    int oc = wid * 32 + o;
    int idx = (b * 128 + oc) * HWHW + hw0 + lane;
    float a = acc[o] + bo[oc];
    out1[idx] = a;
    out0[idx] = fmaf(gm, a, x[idx]);
  }
}

extern "C" void kernel_launch(void* const* d_in, const int* in_sizes, int n_in,
                              void* d_out, int out_size, void* d_ws, size_t ws_size,
                              hipStream_t stream) {
  const float* x     = (const float*)d_in[0];
  const float* gamma = (const float*)d_in[1];
  const float* wq    = (const float*)d_in[2];
  const float* wk    = (const float*)d_in[3];
  const float* wv    = (const float*)d_in[4];
  const float* wo    = (const float*)d_in[5];
  const float* bo    = (const float*)d_in[6];
  const float* wdw   = (const float*)d_in[7];
  const float* bdw   = (const float*)d_in[8];
  const float* wproj = (const float*)d_in[9];
  const float* cw0   = (const float*)d_in[10];
  const float* cb0   = (const float*)d_in[11];
  const float* cw1   = (const float*)d_in[12];
  const float* cb1   = (const float*)d_in[13];
  const float* cw2   = (const float*)d_in[14];
  const float* cb2   = (const float*)d_in[15];
  float* ws   = (float*)d_ws;
  float* q    = ws;
  float* qt   = ws + 589824;
  float* vn0  = ws + 1179648;
  float* vn1  = ws + 1180800;
  float* px   = ws + 1181952;
  float* py   = ws + 1183104;
  float* kt   = ws + 1184256;
  float* vt   = ws + 1221120;
  float* outh = ws + 1257984;
  float* L    = ws + 1847808;
  float* out  = (float*)d_out;

  qproj_kernel<<<dim3(9, 32, 8), 256, 0, stream>>>(x, wq, q, qt);
  offset_kernel<<<8, 192, 0, stream>>>(q, wdw, bdw, wproj, vn0, vn1, px, py);
  kv_kernel<<<8, 256, 0, stream>>>(x, wk, wv, px, py, kt, vt);
  logits_kernel<<<dim3(144, 8), 256, 0, stream>>>(qt, kt, vn0, vn1,
                                                  cw0, cb0, cw1, cb1, cw2, cb2, L);
  softmax_pv_kernel<<<dim3(144, 8), 256, 0, stream>>>(L, vt, outh);
  out_kernel<<<dim3(36, 2), 256, 0, stream>>>(outh, wo, bo, x, gamma, out);
}

// Round 2
// 410.400 us; speedup vs baseline: 1.3942x; 1.3942x over previous
//
#include <hip/hip_runtime.h>
#include <math.h>

// dims
#define HWHW 2304   // 48*48
#define JD   144    // 12*12
#define LSP  148    // Ls row stride in dwords (148*4 B = 592 B, 16B-aligned rows)

typedef __attribute__((ext_vector_type(8))) short short8;
typedef __attribute__((ext_vector_type(4))) float f32x4;

__device__ inline ushort f2bf(float f) {
  uint u = __float_as_uint(f);
  u += 0x7fffu + ((u >> 16) & 1u);   // RNE
  return (ushort)(u >> 16);
}

// ws layout (float offsets)
// q    [8][32][2304]   @ 0
// qt   [8][2304][32]   @ 589824
// vn0  [8][144]        @ 1179648
// vn1  [8][144]        @ 1180800
// px   [8][144]        @ 1181952
// py   [8][144]        @ 1183104
// kt   [8][144][32]    @ 1184256
// vtT  [8][32][144]    @ 1221120
// outh [2][2304][128]  @ 1257984   (end 1847808 floats = 7.4 MB)

__global__ __launch_bounds__(256) void qproj_kernel(
    const float* __restrict__ x, const float* __restrict__ wq,
    float* __restrict__ q, float* __restrict__ qt) {
  int hw = blockIdx.x * 256 + threadIdx.x;
  int o = blockIdx.y, bg = blockIdx.z;
  int b = bg >> 2, g = bg & 3;
  const float* wrow = wq + (g * 32 + o) * 32;   // uniform -> scalar loads
  const float* xp = x + (b * 128 + g * 32) * HWHW + hw;
  float acc = 0.f;
#pragma unroll
  for (int c = 0; c < 32; ++c) acc += wrow[c] * xp[c * HWHW];
  q[(bg * 32 + o) * HWHW + hw] = acc;
  qt[(bg * HWHW + hw) * 32 + o] = acc;
}

__global__ __launch_bounds__(192) void offset_kernel(
    const float* __restrict__ q, const float* __restrict__ wdw,
    const float* __restrict__ bdw, const float* __restrict__ wproj,
    float* __restrict__ vn0, float* __restrict__ vn1,
    float* __restrict__ px, float* __restrict__ py) {
  int t = threadIdx.x;
  int bg = blockIdx.x;
  if (t >= JD) return;
  int hd = t / 12, wd = t - (t / 12) * 12;
  float a0 = 0.f, a1 = 0.f;
  for (int c = 0; c < 32; ++c) {
    const float* qp = q + (bg * 32 + c) * HWHW;
    const float* wp = wdw + c * 36;             // uniform -> scalar
    float s = 0.f;
#pragma unroll
    for (int ky = 0; ky < 6; ++ky) {
      int hy = hd * 4 - 1 + ky;
      if (hy < 0 || hy >= 48) continue;
#pragma unroll
      for (int kx = 0; kx < 6; ++kx) {
        int wx = wd * 4 - 1 + kx;
        if (wx < 0 || wx >= 48) continue;
        s += wp[ky * 6 + kx] * qp[hy * 48 + wx];
      }
    }
    s += bdw[c];
    s = 0.5f * s * (1.f + erff(s * 0.70710678118654752f));  // exact GELU
    a0 += wproj[c] * s;
    a1 += wproj[32 + c] * s;
  }
  float off0 = tanhf(a0) * 4.f;
  float off1 = tanhf(a1) * 4.f;
  float n0 = 2.f * ((float)wd + off0) / 11.f - 1.f;
  float n1 = 2.f * ((float)hd + off1) / 11.f - 1.f;
  vn0[bg * JD + t] = n0;
  vn1[bg * JD + t] = n1;
  px[bg * JD + t] = ((n0 + 1.f) * 48.f - 1.f) * 0.5f;
  py[bg * JD + t] = ((n1 + 1.f) * 48.f - 1.f) * 0.5f;
}

__global__ __launch_bounds__(256) void kv_kernel(
    const float* __restrict__ x, const float* __restrict__ wk,
    const float* __restrict__ wv, const float* __restrict__ px,
    const float* __restrict__ py, float* __restrict__ kt,
    float* __restrict__ vtT) {
  __shared__ float kv[32][JD];
  __shared__ float wkl[32][33], wvl[32][33];
  int bg = blockIdx.x, b = bg >> 2, g = bg & 3;
  int t = threadIdx.x;
  for (int u = t; u < 1024; u += 256) {
    int d = u >> 5, c = u & 31;
    wkl[d][c] = wk[g * 1024 + u];
    wvl[d][c] = wv[g * 1024 + u];
  }
  for (int u = t; u < 32 * JD; u += 256) {
    int c = u / JD, j = u - c * JD;
    float fx = px[bg * JD + j], fy = py[bg * JD + j];
    float x0 = floorf(fx), y0 = floorf(fy);
    float wx = fx - x0, wy = fy - y0;
    int xi = (int)x0, yi = (int)y0;
    const float* xp = x + (b * 128 + g * 32 + c) * HWHW;
    float v00 = 0.f, v10 = 0.f, v01 = 0.f, v11 = 0.f;
    bool okx0 = (xi >= 0) & (xi < 48), okx1 = (xi + 1 >= 0) & (xi + 1 < 48);
    if (yi >= 0 && yi < 48) {
      if (okx0) v00 = xp[yi * 48 + xi];
      if (okx1) v10 = xp[yi * 48 + xi + 1];
    }
    if (yi + 1 >= 0 && yi + 1 < 48) {
      if (okx0) v01 = xp[(yi + 1) * 48 + xi];
      if (okx1) v11 = xp[(yi + 1) * 48 + xi + 1];
    }
    kv[c][j] = v00 * (1.f - wx) * (1.f - wy) + v10 * wx * (1.f - wy)
             + v01 * (1.f - wx) * wy + v11 * wx * wy;
  }
  __syncthreads();
  for (int u = t; u < 32 * JD; u += 256) {
    int j = u >> 5, d = u & 31;
    float ak = 0.f, av = 0.f;
#pragma unroll
    for (int c = 0; c < 32; ++c) {
      float val = kv[c][j];
      ak += wkl[d][c] * val;
      av += wvl[d][c] * val;
    }
    kt[bg * 4608 + u] = ak;          // [j][d]
    vtT[bg * 4608 + d * JD + j] = av; // [d][j] transposed
  }
}

// Fused: sim (MFMA) + CPB bias MLP (MFMA middle layer) + softmax + PV (MFMA)
// block = (bg, 48 q-rows), 192 threads = 3 waves, wave owns 16 rows.
__global__ __launch_bounds__(192) void attn_fused_kernel(
    const float* __restrict__ qt, const float* __restrict__ kt,
    const float* __restrict__ vtT,
    const float* __restrict__ vn0, const float* __restrict__ vn1,
    const float* __restrict__ w0, const float* __restrict__ b0,
    const float* __restrict__ w1, const float* __restrict__ b1,
    const float* __restrict__ w2, const float* __restrict__ b2,
    float* __restrict__ outh) {
  __shared__ __align__(16) char smem[43008];
  float* Ls = (float*)smem;                    // [48][LSP] fp32; P bf16 lives at dwords 64..143
  ushort* kbf = (ushort*)(smem + 28416);       // [144][32] bf16 (phase 1)
  ushort* vbfT = (ushort*)(smem + 28416);      // [32][160] bf16 (phase 3+), overlaps kbf
  ushort* qbf = (ushort*)(smem + 38656);       // [48][32] bf16
  float* sv0 = (float*)(smem + 41728);         // [144]
  float* sv1 = sv0 + 144;                      // [144]

  int bg = blockIdx.y, b = bg >> 2, g = bg & 3;
  int i0 = blockIdx.x * 48;
  int t = threadIdx.x;
  int w = t >> 6, lane = t & 63;
  int lam = lane & 15, quad = lane >> 4;

  // ---- stage q,k,sv ----
  for (int u = t; u < JD * 32; u += 192) kbf[u] = f2bf(kt[bg * 4608 + u]);
  for (int u = t; u < 48 * 32; u += 192) qbf[u] = f2bf(qt[(bg * HWHW + i0) * 32 + u]);
  if (t < JD) { sv0[t] = vn0[bg * JD + t]; sv1[t] = vn1[bg * JD + t]; }

  // ---- per-lane resident weights (no per-iteration reloads) ----
  float w00r[8], w01r[8], b0r[8];
#pragma unroll
  for (int j = 0; j < 8; ++j) {
    int k = quad * 8 + j;
    w00r[j] = w0[k]; w01r[j] = w0[32 + k]; b0r[j] = b0[k];
  }
  short8 w1f0, w1f1;   // B-frags of W1 (K=32, two N-halves)
#pragma unroll
  for (int j = 0; j < 8; ++j) {
    int k = quad * 8 + j;
    w1f0[j] = (short)f2bf(w1[k * 32 + lam]);
    w1f1[j] = (short)f2bf(w1[k * 32 + 16 + lam]);
  }
  float b1n0 = b1[lam], b1n1 = b1[16 + lam];
  float w2n0 = w2[lam], w2n1 = w2[16 + lam];
  float b2s = b2[0];

  __syncthreads();   // B1

  // ---- P1: sim = q·kT (scaled) via MFMA ----
  const float scale = 0.17677669529663687f;   // 32^-0.5
  {
    short8 aq = *(const short8*)(qbf + (w * 16 + lam) * 32 + quad * 8);
#pragma unroll 1
    for (int jt = 0; jt < 9; ++jt) {
      short8 bk = *(const short8*)(kbf + (jt * 16 + lam) * 32 + quad * 8);
      f32x4 acc = {0.f, 0.f, 0.f, 0.f};
      acc = __builtin_amdgcn_mfma_f32_16x16x32_bf16(aq, bk, acc, 0, 0, 0);
#pragma unroll
      for (int r = 0; r < 4; ++r)
        Ls[(w * 16 + quad * 4 + r) * LSP + jt * 16 + lam] = acc[r] * scale;
    }
  }
  __syncthreads();   // B2

  // ---- P2: CPB bias, middle 32x32 layer on MFMA; 36 sub-iters of 64 pairs ----
#pragma unroll 1
  for (int s = 0; s < 36; ++s) {
    int P0 = s * 64 + lane;
    int ii0 = P0 / 144, jj0 = P0 - ii0 * 144;
    int ig = i0 + w * 16 + ii0;
    int iy = ig / 48, ix = ig - iy * 48;
    float p0 = (float)ix * (2.f / 47.f) - 1.f - sv0[jj0];
    float p1 = (float)iy * (2.f / 47.f) - 1.f - sv1[jj0];
    float s0f = copysignf(log1pf(fabsf(p0)), p0);
    float s1f = copysignf(log1pf(fabsf(p1)), p1);
    f32x4 dA[4], dB[4];
#pragma unroll
    for (int mt = 0; mt < 4; ++mt) {
      float s0 = __shfl(s0f, mt * 16 + lam, 64);
      float s1 = __shfl(s1f, mt * 16 + lam, 64);
      short8 af;   // layer-1 output, built directly in A-frag layout
#pragma unroll
      for (int j = 0; j < 8; ++j) {
        float h = fmaxf(fmaf(s0, w00r[j], fmaf(s1, w01r[j], b0r[j])), 0.f);
        af[j] = (short)f2bf(h);
      }
      f32x4 z = {0.f, 0.f, 0.f, 0.f};
      dA[mt] = __builtin_amdgcn_mfma_f32_16x16x32_bf16(af, w1f0, z, 0, 0, 0);
      dB[mt] = __builtin_amdgcn_mfma_f32_16x16x32_bf16(af, w1f1, z, 0, 0, 0);
    }
    float v[16];
#pragma unroll
    for (int mt = 0; mt < 4; ++mt)
#pragma unroll
      for (int r = 0; r < 4; ++r)
        v[mt * 4 + r] = fmaxf(dA[mt][r] + b1n0, 0.f) * w2n0
                      + fmaxf(dB[mt][r] + b1n1, 0.f) * w2n1;
    // butterfly reduce-scatter across the 16-lane column group: lane lam ends with idx=lam
#define RSTEP(K, HALF)                                                        \
    { bool hi = (lam & K) != 0;                                               \
      _Pragma("unroll")                                                       \
      for (int i2 = 0; i2 < HALF; ++i2) {                                     \
        float send = hi ? v[i2] : v[i2 + HALF];                               \
        float recv = __shfl_xor(send, K, 64);                                 \
        v[i2] = (hi ? v[i2 + HALF] : v[i2]) + recv;                           \
      } }
    RSTEP(8, 8) RSTEP(4, 4) RSTEP(2, 2) RSTEP(1, 1)
#undef RSTEP
    float biasv = v[0] + b2s;
    int pair64 = ((lam >> 2) << 4) + (quad << 2) + (lam & 3);
    int P = s * 64 + pair64;
    int ii = P / 144, jj = P - ii * 144;
    Ls[(w * 16 + ii) * LSP + jj] += biasv;
  }
  __syncthreads();   // B3

  // ---- stage vT as bf16 (overlaps kbf, now dead); zero K-pad ----
  for (int u = t; u < 32 * JD; u += 192) {
    int d = u / JD, j = u - d * JD;
    vbfT[d * 160 + j] = f2bf(vtT[bg * 4608 + u]);
  }
  for (int u = t; u < 512; u += 192)
    vbfT[(u >> 4) * 160 + 144 + (u & 15)] = 0;

  // ---- P3: softmax per row; P packed bf16 in-place (upper half of row) ----
#pragma unroll 1
  for (int rr = 0; rr < 16; ++rr) {
    int row = w * 16 + rr;
    const float* Lp = Ls + row * LSP;
    float l0 = Lp[lane], l1 = Lp[64 + lane];
    float l2 = (lane < 16) ? Lp[128 + lane] : -INFINITY;
    float m = fmaxf(fmaxf(l0, l1), l2);
#pragma unroll
    for (int k = 32; k >= 1; k >>= 1) m = fmaxf(m, __shfl_xor(m, k, 64));
    float e0 = __expf(l0 - m), e1 = __expf(l1 - m);
    float e2 = (lane < 16) ? __expf(l2 - m) : 0.f;
    float sum = e0 + e1 + e2;
#pragma unroll
    for (int k = 32; k >= 1; k >>= 1) sum += __shfl_xor(sum, k, 64);
    float inv = 1.f / sum;
    ushort* pb = (ushort*)(Lp + 64);
    pb[lane] = f2bf(e0 * inv);
    pb[64 + lane] = f2bf(e1 * inv);
    if (lane < 32) pb[128 + lane] = (lane < 16) ? f2bf(e2 * inv) : (ushort)0;
  }
  __syncthreads();   // B4

  // ---- P4: O = P·v via MFMA (K=160 with zero pad) ----
  f32x4 o0 = {0.f, 0.f, 0.f, 0.f}, o1 = {0.f, 0.f, 0.f, 0.f};
  {
    const ushort* pb = (const ushort*)(Ls + (w * 16 + lam) * LSP + 64);
#pragma unroll
    for (int kb = 0; kb < 5; ++kb) {
      short8 ap = *(const short8*)(pb + kb * 32 + quad * 8);
      short8 bv0 = *(const short8*)(vbfT + lam * 160 + kb * 32 + quad * 8);
      short8 bv1 = *(const short8*)(vbfT + (16 + lam) * 160 + kb * 32 + quad * 8);
      o0 = __builtin_amdgcn_mfma_f32_16x16x32_bf16(ap, bv0, o0, 0, 0, 0);
      o1 = __builtin_amdgcn_mfma_f32_16x16x32_bf16(ap, bv1, o1, 0, 0, 0);
    }
  }
#pragma unroll
  for (int r = 0; r < 4; ++r) {
    int ig = i0 + w * 16 + quad * 4 + r;
    float* op = outh + ((long)b * HWHW + ig) * 128 + g * 32;
    op[lam] = o0[r];
    op[16 + lam] = o1[r];
  }
}

__global__ __launch_bounds__(256) void out_kernel(
    const float* __restrict__ outh, const float* __restrict__ wo,
    const float* __restrict__ bo, const float* __restrict__ x,
    const float* __restrict__ gamma, float* __restrict__ out) {
  __shared__ float tile[64 * 129];   // +1 pad: row-read bank-conflict-free
  int b = blockIdx.y;
  int hw0 = blockIdx.x * 64;
  int t = threadIdx.x;
  int wid = t >> 6, lane = t & 63;
  for (int u = t; u < 2048; u += 256) {
    int r = u >> 5, c4 = (u & 31) * 4;
    const float4 v = *(const float4*)(outh + (b * HWHW + hw0 + r) * 128 + c4);
    float* dst = tile + r * 129 + c4;
    dst[0] = v.x; dst[1] = v.y; dst[2] = v.z; dst[3] = v.w;
  }
  __syncthreads();
  float acc[32];
#pragma unroll
  for (int o = 0; o < 32; ++o) acc[o] = 0.f;
  const float* wop = wo + wid * 32 * 128;   // uniform per wave -> scalar
  const float* row = tile + lane * 129;
#pragma unroll 1
  for (int c4 = 0; c4 < 128; c4 += 4) {
    float v0 = row[c4], v1 = row[c4 + 1], v2 = row[c4 + 2], v3 = row[c4 + 3];
#pragma unroll
    for (int o = 0; o < 32; ++o) {
      acc[o] += wop[o * 128 + c4] * v0 + wop[o * 128 + c4 + 1] * v1
              + wop[o * 128 + c4 + 2] * v2 + wop[o * 128 + c4 + 3] * v3;
    }
  }
  float gm = gamma[0];
  float* out0 = out;
  float* out1 = out + 2 * 128 * HWHW;
#pragma unroll
  for (int o = 0; o < 32; ++o) {
    int oc = wid * 32 + o;
    int idx = (b * 128 + oc) * HWHW + hw0 + lane;
    float a = acc[o] + bo[oc];
    out1[idx] = a;
    out0[idx] = fmaf(gm, a, x[idx]);
  }
}

extern "C" void kernel_launch(void* const* d_in, const int* in_sizes, int n_in,
                              void* d_out, int out_size, void* d_ws, size_t ws_size,
                              hipStream_t stream) {
  const float* x     = (const float*)d_in[0];
  const float* gamma = (const float*)d_in[1];
  const float* wq    = (const float*)d_in[2];
  const float* wk    = (const float*)d_in[3];
  const float* wv    = (const float*)d_in[4];
  const float* wo    = (const float*)d_in[5];
  const float* bo    = (const float*)d_in[6];
  const float* wdw   = (const float*)d_in[7];
  const float* bdw   = (const float*)d_in[8];
  const float* wproj = (const float*)d_in[9];
  const float* cw0   = (const float*)d_in[10];
  const float* cb0   = (const float*)d_in[11];
  const float* cw1   = (const float*)d_in[12];
  const float* cb1   = (const float*)d_in[13];
  const float* cw2   = (const float*)d_in[14];
  const float* cb2   = (const float*)d_in[15];
  float* ws   = (float*)d_ws;
  float* q    = ws;
  float* qt   = ws + 589824;
  float* vn0  = ws + 1179648;
  float* vn1  = ws + 1180800;
  float* px   = ws + 1181952;
  float* py   = ws + 1183104;
  float* kt   = ws + 1184256;
  float* vtT  = ws + 1221120;
  float* outh = ws + 1257984;
  float* out  = (float*)d_out;

  qproj_kernel<<<dim3(9, 32, 8), 256, 0, stream>>>(x, wq, q, qt);
  offset_kernel<<<8, 192, 0, stream>>>(q, wdw, bdw, wproj, vn0, vn1, px, py);
  kv_kernel<<<8, 256, 0, stream>>>(x, wk, wv, px, py, kt, vtT);
  attn_fused_kernel<<<dim3(48, 8), 192, 0, stream>>>(qt, kt, vtT, vn0, vn1,
                                                     cw0, cb0, cw1, cb1, cw2, cb2, outh);
  out_kernel<<<dim3(36, 2), 256, 0, stream>>>(outh, wo, bo, x, gamma, out);
}

// Round 3
// 271.869 us; speedup vs baseline: 2.1046x; 1.5096x over previous
//
#include <hip/hip_runtime.h>
#include <math.h>

// dims
#define HWHW 2304   // 48*48
#define JD   144    // 12*12
#define LSP  148    // Ls row stride in dwords (148*4 B = 592 B, 16B-aligned rows)

typedef __attribute__((ext_vector_type(8))) short short8;
typedef __attribute__((ext_vector_type(4))) float f32x4;

__device__ inline ushort f2bf(float f) {
  uint u = __float_as_uint(f);
  u += 0x7fffu + ((u >> 16) & 1u);   // RNE
  return (ushort)(u >> 16);
}

// ws layout (float offsets)
// q    [8][32][2304]   @ 0
// qt   [8][2304][32]   @ 589824
// vn0  [8][144]        @ 1179648
// vn1  [8][144]        @ 1180800
// px   [8][144]        @ 1181952
// py   [8][144]        @ 1183104
// kt   [8][144][32]    @ 1184256
// vtT  [8][32][144]    @ 1221120
// outh [2][2304][128]  @ 1257984   (end 1847808 floats = 7.4 MB)

__global__ __launch_bounds__(256) void qproj_kernel(
    const float* __restrict__ x, const float* __restrict__ wq,
    float* __restrict__ q, float* __restrict__ qt) {
  int hw = blockIdx.x * 256 + threadIdx.x;
  int o = blockIdx.y, bg = blockIdx.z;
  int b = bg >> 2, g = bg & 3;
  const float* wrow = wq + (g * 32 + o) * 32;   // uniform -> scalar loads
  const float* xp = x + (b * 128 + g * 32) * HWHW + hw;
  float acc = 0.f;
#pragma unroll
  for (int c = 0; c < 32; ++c) acc += wrow[c] * xp[c * HWHW];
  q[(bg * 32 + o) * HWHW + hw] = acc;
  qt[(bg * HWHW + hw) * 32 + o] = acc;
}

// grid (12 hd, 8 bg), 384 thr: t = pos*32 + c. Stage 6 q-rows x 32ch in LDS,
// depthwise 6x6 conv per (pos,c), GELU, shfl-reduce 1x1 proj over c.
__global__ __launch_bounds__(384) void offset_kernel(
    const float* __restrict__ q, const float* __restrict__ wdw,
    const float* __restrict__ bdw, const float* __restrict__ wproj,
    float* __restrict__ vn0, float* __restrict__ vn1,
    float* __restrict__ px, float* __restrict__ py) {
  __shared__ float qs[32][288];    // [c][ry*48+col], stride%32==0 but reads broadcast
  __shared__ float wdws[32][36];
  int hd = blockIdx.x, bg = blockIdx.y;
  int t = threadIdx.x;
  for (int u = t; u < 9216; u += 384) {
    int c = u / 288, r = u - c * 288;
    int ry = r / 48, col = r - ry * 48;
    int hy = hd * 4 - 1 + ry;
    qs[c][r] = (hy >= 0 && hy < 48) ? q[(bg * 32 + c) * HWHW + hy * 48 + col] : 0.f;
  }
  for (int u = t; u < 1152; u += 384) wdws[u / 36][u % 36] = wdw[u];
  __syncthreads();
  int wd = t >> 5, c = t & 31;
  float s = 0.f;
#pragma unroll
  for (int ky = 0; ky < 6; ++ky) {
#pragma unroll
    for (int kx = 0; kx < 6; ++kx) {
      int wx = wd * 4 - 1 + kx;
      if (wx >= 0 && wx < 48)
        s += wdws[c][ky * 6 + kx] * qs[c][ky * 48 + wx];
    }
  }
  s += bdw[c];
  s = 0.5f * s * (1.f + erff(s * 0.70710678118654752f));  // exact GELU
  float g0 = wproj[c] * s;
  float g1 = wproj[32 + c] * s;
#pragma unroll
  for (int k = 16; k >= 1; k >>= 1) {
    g0 += __shfl_xor(g0, k, 64);
    g1 += __shfl_xor(g1, k, 64);
  }
  if (c == 0) {
    float off0 = tanhf(g0) * 4.f;
    float off1 = tanhf(g1) * 4.f;
    float n0 = 2.f * ((float)wd + off0) / 11.f - 1.f;
    float n1 = 2.f * ((float)hd + off1) / 11.f - 1.f;
    int idx = bg * JD + hd * 12 + wd;
    vn0[idx] = n0;
    vn1[idx] = n1;
    px[idx] = ((n0 + 1.f) * 48.f - 1.f) * 0.5f;
    py[idx] = ((n1 + 1.f) * 48.f - 1.f) * 0.5f;
  }
}

// grid (9 j-chunks, 8 bg), 256 thr: bilinear-sample 16 j x 32 c, then k/v proj.
__global__ __launch_bounds__(256) void kv_kernel(
    const float* __restrict__ x, const float* __restrict__ wk,
    const float* __restrict__ wv, const float* __restrict__ px,
    const float* __restrict__ py, float* __restrict__ kt,
    float* __restrict__ vtT) {
  __shared__ float kvs[32][16];
  __shared__ float wkl[32][33], wvl[32][33];   // [d][c]
  int jc = blockIdx.x, bg = blockIdx.y, b = bg >> 2, g = bg & 3;
  int t = threadIdx.x;
  for (int u = t; u < 1024; u += 256) {
    int d = u >> 5, c = u & 31;
    wkl[d][c] = wk[g * 1024 + u];
    wvl[d][c] = wv[g * 1024 + u];
  }
  for (int u = t; u < 512; u += 256) {
    int c = u >> 4, j16 = u & 15;
    int j = jc * 16 + j16;
    float fx = px[bg * JD + j], fy = py[bg * JD + j];
    float x0 = floorf(fx), y0 = floorf(fy);
    float wx = fx - x0, wy = fy - y0;
    int xi = (int)x0, yi = (int)y0;
    const float* xp = x + (b * 128 + g * 32 + c) * HWHW;
    float v00 = 0.f, v10 = 0.f, v01 = 0.f, v11 = 0.f;
    bool okx0 = (xi >= 0) & (xi < 48), okx1 = (xi + 1 >= 0) & (xi + 1 < 48);
    if (yi >= 0 && yi < 48) {
      if (okx0) v00 = xp[yi * 48 + xi];
      if (okx1) v10 = xp[yi * 48 + xi + 1];
    }
    if (yi + 1 >= 0 && yi + 1 < 48) {
      if (okx0) v01 = xp[(yi + 1) * 48 + xi];
      if (okx1) v11 = xp[(yi + 1) * 48 + xi + 1];
    }
    kvs[c][j16] = v00 * (1.f - wx) * (1.f - wy) + v10 * wx * (1.f - wy)
                + v01 * (1.f - wx) * wy + v11 * wx * wy;
  }
  __syncthreads();
  for (int u = t; u < 512; u += 256) {
    int j16 = u >> 5, d = u & 31;
    int j = jc * 16 + j16;
    float ak = 0.f, av = 0.f;
#pragma unroll
    for (int c = 0; c < 32; ++c) {
      float val = kvs[c][j16];
      ak += wkl[d][c] * val;
      av += wvl[d][c] * val;
    }
    kt[bg * 4608 + j * 32 + d] = ak;    // [j][d]
    vtT[bg * 4608 + d * JD + j] = av;   // [d][j]
  }
}

// Fused: sim (MFMA) + CPB bias MLP (MFMA middle layer) + softmax + PV (MFMA)
// block = (bg, 48 q-rows), 192 threads = 3 waves, wave owns 16 rows.
__global__ __launch_bounds__(192) void attn_fused_kernel(
    const float* __restrict__ qt, const float* __restrict__ kt,
    const float* __restrict__ vtT,
    const float* __restrict__ vn0, const float* __restrict__ vn1,
    const float* __restrict__ w0, const float* __restrict__ b0,
    const float* __restrict__ w1, const float* __restrict__ b1,
    const float* __restrict__ w2, const float* __restrict__ b2,
    float* __restrict__ outh) {
  __shared__ __align__(16) char smem[43008];
  float* Ls = (float*)smem;                    // [48][LSP] fp32; P bf16 at dwords 64..143
  ushort* kbf = (ushort*)(smem + 28416);       // [144][32] bf16 (phase 1)
  ushort* vbfT = (ushort*)(smem + 28416);      // [32][160] bf16 (phase 3+), overlaps kbf
  ushort* qbf = (ushort*)(smem + 38656);       // [48][32] bf16
  float* sv0 = (float*)(smem + 41728);         // [144]
  float* sv1 = sv0 + 144;                      // [144]

  int bg = blockIdx.y, b = bg >> 2, g = bg & 3;
  int i0 = blockIdx.x * 48;
  int t = threadIdx.x;
  int w = t >> 6, lane = t & 63;
  int lam = lane & 15, quad = lane >> 4;

  // ---- stage q,k,sv ----
  for (int u = t; u < JD * 32; u += 192) kbf[u] = f2bf(kt[bg * 4608 + u]);
  for (int u = t; u < 48 * 32; u += 192) qbf[u] = f2bf(qt[(bg * HWHW + i0) * 32 + u]);
  if (t < JD) { sv0[t] = vn0[bg * JD + t]; sv1[t] = vn1[bg * JD + t]; }

  // ---- per-lane resident weights ----
  float w00r[8], w01r[8], b0r[8];
#pragma unroll
  for (int j = 0; j < 8; ++j) {
    int k = quad * 8 + j;
    w00r[j] = w0[k]; w01r[j] = w0[32 + k]; b0r[j] = b0[k];
  }
  short8 w1f0, w1f1;   // B-frags of W1 (K=32, two N-halves)
#pragma unroll
  for (int j = 0; j < 8; ++j) {
    int k = quad * 8 + j;
    w1f0[j] = (short)f2bf(w1[k * 32 + lam]);
    w1f1[j] = (short)f2bf(w1[k * 32 + 16 + lam]);
  }
  float b1n0 = b1[lam], b1n1 = b1[16 + lam];
  float w2n0 = w2[lam], w2n1 = w2[16 + lam];
  float b2s = b2[0];

  __syncthreads();   // B1

  // ---- P1: sim = q·kT (scaled) via MFMA ----
  const float scale = 0.17677669529663687f;   // 32^-0.5
  {
    short8 aq = *(const short8*)(qbf + (w * 16 + lam) * 32 + quad * 8);
#pragma unroll 1
    for (int jt = 0; jt < 9; ++jt) {
      short8 bk = *(const short8*)(kbf + (jt * 16 + lam) * 32 + quad * 8);
      f32x4 acc = {0.f, 0.f, 0.f, 0.f};
      acc = __builtin_amdgcn_mfma_f32_16x16x32_bf16(aq, bk, acc, 0, 0, 0);
#pragma unroll
      for (int r = 0; r < 4; ++r)
        Ls[(w * 16 + quad * 4 + r) * LSP + jt * 16 + lam] = acc[r] * scale;
    }
  }
  __syncthreads();   // B2

  // ---- P2: CPB bias, middle 32x32 layer on MFMA; 36 sub-iters of 64 pairs ----
#pragma unroll 1
  for (int s = 0; s < 36; ++s) {
    int P0 = s * 64 + lane;
    int ii0 = P0 / 144, jj0 = P0 - ii0 * 144;
    int ig = i0 + w * 16 + ii0;
    int iy = ig / 48, ix = ig - iy * 48;
    float p0 = (float)ix * (2.f / 47.f) - 1.f - sv0[jj0];
    float p1 = (float)iy * (2.f / 47.f) - 1.f - sv1[jj0];
    float s0f = copysignf(log1pf(fabsf(p0)), p0);
    float s1f = copysignf(log1pf(fabsf(p1)), p1);
    f32x4 dA[4], dB[4];
#pragma unroll
    for (int mt = 0; mt < 4; ++mt) {
      float s0 = __shfl(s0f, mt * 16 + lam, 64);
      float s1 = __shfl(s1f, mt * 16 + lam, 64);
      short8 af;   // layer-1 output, built directly in A-frag layout
#pragma unroll
      for (int j = 0; j < 8; ++j) {
        float h = fmaxf(fmaf(s0, w00r[j], fmaf(s1, w01r[j], b0r[j])), 0.f);
        af[j] = (short)f2bf(h);
      }
      f32x4 z = {0.f, 0.f, 0.f, 0.f};
      dA[mt] = __builtin_amdgcn_mfma_f32_16x16x32_bf16(af, w1f0, z, 0, 0, 0);
      dB[mt] = __builtin_amdgcn_mfma_f32_16x16x32_bf16(af, w1f1, z, 0, 0, 0);
    }
    float v[16];
#pragma unroll
    for (int mt = 0; mt < 4; ++mt)
#pragma unroll
      for (int r = 0; r < 4; ++r)
        v[mt * 4 + r] = fmaxf(dA[mt][r] + b1n0, 0.f) * w2n0
                      + fmaxf(dB[mt][r] + b1n1, 0.f) * w2n1;
#define RSTEP(K, HALF)                                                        \
    { bool hi = (lam & K) != 0;                                               \
      _Pragma("unroll")                                                       \
      for (int i2 = 0; i2 < HALF; ++i2) {                                     \
        float send = hi ? v[i2] : v[i2 + HALF];                               \
        float recv = __shfl_xor(send, K, 64);                                 \
        v[i2] = (hi ? v[i2 + HALF] : v[i2]) + recv;                           \
      } }
    RSTEP(8, 8) RSTEP(4, 4) RSTEP(2, 2) RSTEP(1, 1)
#undef RSTEP
    float biasv = v[0] + b2s;
    int pair64 = ((lam >> 2) << 4) + (quad << 2) + (lam & 3);
    int P = s * 64 + pair64;
    int ii = P / 144, jj = P - ii * 144;
    Ls[(w * 16 + ii) * LSP + jj] += biasv;
  }
  __syncthreads();   // B3

  // ---- stage vT as bf16 (overlaps kbf, now dead); zero K-pad ----
  for (int u = t; u < 32 * JD; u += 192) {
    int d = u / JD, j = u - d * JD;
    vbfT[d * 160 + j] = f2bf(vtT[bg * 4608 + u]);
  }
  for (int u = t; u < 512; u += 192)
    vbfT[(u >> 4) * 160 + 144 + (u & 15)] = 0;

  // ---- P3: softmax per row; P packed bf16 in-place (upper half of row) ----
#pragma unroll 1
  for (int rr = 0; rr < 16; ++rr) {
    int row = w * 16 + rr;
    const float* Lp = Ls + row * LSP;
    float l0 = Lp[lane], l1 = Lp[64 + lane];
    float l2 = (lane < 16) ? Lp[128 + lane] : -INFINITY;
    float m = fmaxf(fmaxf(l0, l1), l2);
#pragma unroll
    for (int k = 32; k >= 1; k >>= 1) m = fmaxf(m, __shfl_xor(m, k, 64));
    float e0 = __expf(l0 - m), e1 = __expf(l1 - m);
    float e2 = (lane < 16) ? __expf(l2 - m) : 0.f;
    float sum = e0 + e1 + e2;
#pragma unroll
    for (int k = 32; k >= 1; k >>= 1) sum += __shfl_xor(sum, k, 64);
    float inv = 1.f / sum;
    ushort* pb = (ushort*)(Lp + 64);
    pb[lane] = f2bf(e0 * inv);
    pb[64 + lane] = f2bf(e1 * inv);
    if (lane < 32) pb[128 + lane] = (lane < 16) ? f2bf(e2 * inv) : (ushort)0;
  }
  __syncthreads();   // B4

  // ---- P4: O = P·v via MFMA (K=160 with zero pad) ----
  f32x4 o0 = {0.f, 0.f, 0.f, 0.f}, o1 = {0.f, 0.f, 0.f, 0.f};
  {
    const ushort* pb = (const ushort*)(Ls + (w * 16 + lam) * LSP + 64);
#pragma unroll
    for (int kb = 0; kb < 5; ++kb) {
      short8 ap = *(const short8*)(pb + kb * 32 + quad * 8);
      short8 bv0 = *(const short8*)(vbfT + lam * 160 + kb * 32 + quad * 8);
      short8 bv1 = *(const short8*)(vbfT + (16 + lam) * 160 + kb * 32 + quad * 8);
      o0 = __builtin_amdgcn_mfma_f32_16x16x32_bf16(ap, bv0, o0, 0, 0, 0);
      o1 = __builtin_amdgcn_mfma_f32_16x16x32_bf16(ap, bv1, o1, 0, 0, 0);
    }
  }
#pragma unroll
  for (int r = 0; r < 4; ++r) {
    int ig = i0 + w * 16 + quad * 4 + r;
    float* op = outh + ((long)b * HWHW + ig) * 128 + g * 32;
    op[lam] = o0[r];
    op[16 + lam] = o1[r];
  }
}

__global__ __launch_bounds__(256) void out_kernel(
    const float* __restrict__ outh, const float* __restrict__ wo,
    const float* __restrict__ bo, const float* __restrict__ x,
    const float* __restrict__ gamma, float* __restrict__ out) {
  __shared__ float tile[64 * 129];   // +1 pad: row-read bank-conflict-free
  int b = blockIdx.y;
  int hw0 = blockIdx.x * 64;
  int t = threadIdx.x;
  int wid = t >> 6, lane = t & 63;
  for (int u = t; u < 2048; u += 256) {
    int r = u >> 5, c4 = (u & 31) * 4;
    const float4 v = *(const float4*)(outh + (b * HWHW + hw0 + r) * 128 + c4);
    float* dst = tile + r * 129 + c4;
    dst[0] = v.x; dst[1] = v.y; dst[2] = v.z; dst[3] = v.w;
  }
  __syncthreads();
  float acc[32];
#pragma unroll
  for (int o = 0; o < 32; ++o) acc[o] = 0.f;
  const float* wop = wo + wid * 32 * 128;   // uniform per wave -> scalar
  const float* row = tile + lane * 129;
#pragma unroll 1
  for (int c4 = 0; c4 < 128; c4 += 4) {
    float v0 = row[c4], v1 = row[c4 + 1], v2 = row[c4 + 2], v3 = row[c4 + 3];
#pragma unroll
    for (int o = 0; o < 32; ++o) {
      acc[o] += wop[o * 128 + c4] * v0 + wop[o * 128 + c4 + 1] * v1
              + wop[o * 128 + c4 + 2] * v2 + wop[o * 128 + c4 + 3] * v3;
    }
  }
  float gm = gamma[0];
  float* out0 = out;
  float* out1 = out + 2 * 128 * HWHW;
#pragma unroll
  for (int o = 0; o < 32; ++o) {
    int oc = wid * 32 + o;
    int idx = (b * 128 + oc) * HWHW + hw0 + lane;
    float a = acc[o] + bo[oc];
    out1[idx] = a;
    out0[idx] = fmaf(gm, a, x[idx]);
  }
}

extern "C" void kernel_launch(void* const* d_in, const int* in_sizes, int n_in,
                              void* d_out, int out_size, void* d_ws, size_t ws_size,
                              hipStream_t stream) {
  const float* x     = (const float*)d_in[0];
  const float* gamma = (const float*)d_in[1];
  const float* wq    = (const float*)d_in[2];
  const float* wk    = (const float*)d_in[3];
  const float* wv    = (const float*)d_in[4];
  const float* wo    = (const float*)d_in[5];
  const float* bo    = (const float*)d_in[6];
  const float* wdw   = (const float*)d_in[7];
  const float* bdw   = (const float*)d_in[8];
  const float* wproj = (const float*)d_in[9];
  const float* cw0   = (const float*)d_in[10];
  const float* cb0   = (const float*)d_in[11];
  const float* cw1   = (const float*)d_in[12];
  const float* cb1   = (const float*)d_in[13];
  const float* cw2   = (const float*)d_in[14];
  const float* cb2   = (const float*)d_in[15];
  float* ws   = (float*)d_ws;
  float* q    = ws;
  float* qt   = ws + 589824;
  float* vn0  = ws + 1179648;
  float* vn1  = ws + 1180800;
  float* px   = ws + 1181952;
  float* py   = ws + 1183104;
  float* kt   = ws + 1184256;
  float* vtT  = ws + 1221120;
  float* outh = ws + 1257984;
  float* out  = (float*)d_out;

  qproj_kernel<<<dim3(9, 32, 8), 256, 0, stream>>>(x, wq, q, qt);
  offset_kernel<<<dim3(12, 8), 384, 0, stream>>>(q, wdw, bdw, wproj, vn0, vn1, px, py);
  kv_kernel<<<dim3(9, 8), 256, 0, stream>>>(x, wk, wv, px, py, kt, vtT);
  attn_fused_kernel<<<dim3(48, 8), 192, 0, stream>>>(qt, kt, vtT, vn0, vn1,
                                                     cw0, cb0, cw1, cb1, cw2, cb2, outh);
  out_kernel<<<dim3(36, 2), 256, 0, stream>>>(outh, wo, bo, x, gamma, out);
}

// Round 4
// 175.676 us; speedup vs baseline: 3.2571x; 1.5476x over previous
//
#include <hip/hip_runtime.h>
#include <math.h>

// dims
#define HWHW 2304   // 48*48
#define JD   144    // 12*12
#define LSP  148    // Ls row stride in dwords

typedef __attribute__((ext_vector_type(8))) short short8;
typedef __attribute__((ext_vector_type(4))) float f32x4;

__device__ inline ushort f2bf(float f) {
  uint u = __float_as_uint(f);
  u += 0x7fffu + ((u >> 16) & 1u);   // RNE
  return (ushort)(u >> 16);
}

// ws layout (float offsets)
// q    [8][32][2304]   @ 0
// qt   [8][2304][32]   @ 589824
// vn0  [8][144]        @ 1179648
// vn1  [8][144]        @ 1180800
// px   [8][144]        @ 1181952
// py   [8][144]        @ 1183104
// kt   [8][144][32]    @ 1184256
// vtT  [8][32][144]    @ 1221120
// outh [2][2304][128]  @ 1257984   (end 1847808 floats = 7.4 MB)

// grid (9 hw-chunks, 4 o-chunks, 8 bg): thread holds 32 x-ch in regs, computes 8 o.
__global__ __launch_bounds__(256) void qproj_kernel(
    const float* __restrict__ x, const float* __restrict__ wq,
    float* __restrict__ q, float* __restrict__ qt) {
  int hw = blockIdx.x * 256 + threadIdx.x;
  int o0 = blockIdx.y * 8, bg = blockIdx.z;
  int b = bg >> 2, g = bg & 3;
  const float* xp = x + (b * 128 + g * 32) * HWHW + hw;
  float xv[32];
#pragma unroll
  for (int c = 0; c < 32; ++c) xv[c] = xp[c * HWHW];
  float acc[8];
#pragma unroll
  for (int oo = 0; oo < 8; ++oo) {
    const float* wrow = wq + (g * 32 + o0 + oo) * 32;   // uniform -> scalar
    float a = 0.f;
#pragma unroll
    for (int c = 0; c < 32; ++c) a += wrow[c] * xv[c];
    acc[oo] = a;
    q[(bg * 32 + o0 + oo) * HWHW + hw] = a;
  }
  float* qtp = qt + (bg * HWHW + hw) * 32 + o0;
  *(float4*)qtp = make_float4(acc[0], acc[1], acc[2], acc[3]);
  *(float4*)(qtp + 4) = make_float4(acc[4], acc[5], acc[6], acc[7]);
}

// grid (12 hd, 8 bg), 384 thr: t = pos*32 + c. Stage 6 q-rows x 32ch in LDS,
// depthwise 6x6 conv per (pos,c), GELU, shfl-reduce 1x1 proj over c.
__global__ __launch_bounds__(384) void offset_kernel(
    const float* __restrict__ q, const float* __restrict__ wdw,
    const float* __restrict__ bdw, const float* __restrict__ wproj,
    float* __restrict__ vn0, float* __restrict__ vn1,
    float* __restrict__ px, float* __restrict__ py) {
  __shared__ float qs[32][288];
  __shared__ float wdws[32][36];
  int hd = blockIdx.x, bg = blockIdx.y;
  int t = threadIdx.x;
  for (int u = t; u < 9216; u += 384) {
    int c = u / 288, r = u - c * 288;
    int ry = r / 48, col = r - ry * 48;
    int hy = hd * 4 - 1 + ry;
    qs[c][r] = (hy >= 0 && hy < 48) ? q[(bg * 32 + c) * HWHW + hy * 48 + col] : 0.f;
  }
  for (int u = t; u < 1152; u += 384) wdws[u / 36][u % 36] = wdw[u];
  __syncthreads();
  int wd = t >> 5, c = t & 31;
  float s = 0.f;
#pragma unroll
  for (int ky = 0; ky < 6; ++ky) {
#pragma unroll
    for (int kx = 0; kx < 6; ++kx) {
      int wx = wd * 4 - 1 + kx;
      if (wx >= 0 && wx < 48)
        s += wdws[c][ky * 6 + kx] * qs[c][ky * 48 + wx];
    }
  }
  s += bdw[c];
  s = 0.5f * s * (1.f + erff(s * 0.70710678118654752f));  // exact GELU
  float g0 = wproj[c] * s;
  float g1 = wproj[32 + c] * s;
#pragma unroll
  for (int k = 16; k >= 1; k >>= 1) {
    g0 += __shfl_xor(g0, k, 64);
    g1 += __shfl_xor(g1, k, 64);
  }
  if (c == 0) {
    float off0 = tanhf(g0) * 4.f;
    float off1 = tanhf(g1) * 4.f;
    float n0 = 2.f * ((float)wd + off0) / 11.f - 1.f;
    float n1 = 2.f * ((float)hd + off1) / 11.f - 1.f;
    int idx = bg * JD + hd * 12 + wd;
    vn0[idx] = n0;
    vn1[idx] = n1;
    px[idx] = ((n0 + 1.f) * 48.f - 1.f) * 0.5f;
    py[idx] = ((n1 + 1.f) * 48.f - 1.f) * 0.5f;
  }
}

// grid (9 j-chunks, 8 bg), 256 thr: bilinear-sample 16 j x 32 c, then k/v proj.
__global__ __launch_bounds__(256) void kv_kernel(
    const float* __restrict__ x, const float* __restrict__ wk,
    const float* __restrict__ wv, const float* __restrict__ px,
    const float* __restrict__ py, float* __restrict__ kt,
    float* __restrict__ vtT) {
  __shared__ float kvs[32][16];
  __shared__ float wkl[32][33], wvl[32][33];   // [d][c]
  int jc = blockIdx.x, bg = blockIdx.y, b = bg >> 2, g = bg & 3;
  int t = threadIdx.x;
  for (int u = t; u < 1024; u += 256) {
    int d = u >> 5, c = u & 31;
    wkl[d][c] = wk[g * 1024 + u];
    wvl[d][c] = wv[g * 1024 + u];
  }
  for (int u = t; u < 512; u += 256) {
    int c = u >> 4, j16 = u & 15;
    int j = jc * 16 + j16;
    float fx = px[bg * JD + j], fy = py[bg * JD + j];
    float x0 = floorf(fx), y0 = floorf(fy);
    float wx = fx - x0, wy = fy - y0;
    int xi = (int)x0, yi = (int)y0;
    const float* xp = x + (b * 128 + g * 32 + c) * HWHW;
    float v00 = 0.f, v10 = 0.f, v01 = 0.f, v11 = 0.f;
    bool okx0 = (xi >= 0) & (xi < 48), okx1 = (xi + 1 >= 0) & (xi + 1 < 48);
    if (yi >= 0 && yi < 48) {
      if (okx0) v00 = xp[yi * 48 + xi];
      if (okx1) v10 = xp[yi * 48 + xi + 1];
    }
    if (yi + 1 >= 0 && yi + 1 < 48) {
      if (okx0) v01 = xp[(yi + 1) * 48 + xi];
      if (okx1) v11 = xp[(yi + 1) * 48 + xi + 1];
    }
    kvs[c][j16] = v00 * (1.f - wx) * (1.f - wy) + v10 * wx * (1.f - wy)
                + v01 * (1.f - wx) * wy + v11 * wx * wy;
  }
  __syncthreads();
  for (int u = t; u < 512; u += 256) {
    int j16 = u >> 5, d = u & 31;
    int j = jc * 16 + j16;
    float ak = 0.f, av = 0.f;
#pragma unroll
    for (int c = 0; c < 32; ++c) {
      float val = kvs[c][j16];
      ak += wkl[d][c] * val;
      av += wvl[d][c] * val;
    }
    kt[bg * 4608 + j * 32 + d] = ak;    // [j][d]
    vtT[bg * 4608 + d * JD + j] = av;   // [d][j]
  }
}

// Fused: sim (MFMA) + CPB bias MLP (MFMA middle layer) + softmax + PV (MFMA)
// block = (bg, 32 q-rows), 256 threads = 4 waves, wave owns 8 rows.
__global__ __launch_bounds__(256) void attn_fused_kernel(
    const float* __restrict__ qt, const float* __restrict__ kt,
    const float* __restrict__ vtT,
    const float* __restrict__ vn0, const float* __restrict__ vn1,
    const float* __restrict__ w0, const float* __restrict__ b0,
    const float* __restrict__ w1, const float* __restrict__ b1,
    const float* __restrict__ w2, const float* __restrict__ b2,
    float* __restrict__ outh) {
  __shared__ __align__(16) char smem[32384];
  float* Ls = (float*)smem;                    // [32][LSP] fp32; P bf16 at dwords 64..143
  ushort* kbf = (ushort*)(smem + 18944);       // [144][32] bf16 (phase 1)
  ushort* vbfT = (ushort*)(smem + 18944);      // [32][160] bf16 (phase 3+), overlaps kbf
  ushort* qbf = (ushort*)(smem + 29184);       // [32][32] bf16
  float* sv0 = (float*)(smem + 31232);         // [144]
  float* sv1 = (float*)(smem + 31808);         // [144]

  int bg = blockIdx.y, b = bg >> 2, g = bg & 3;
  int i0 = blockIdx.x * 32;
  int t = threadIdx.x;
  int w = t >> 6, lane = t & 63;
  int lam = lane & 15, quad = lane >> 4;

  // ---- stage q,k,sv ----
  for (int u = t; u < JD * 32; u += 256) kbf[u] = f2bf(kt[bg * 4608 + u]);
  for (int u = t; u < 32 * 32; u += 256) qbf[u] = f2bf(qt[(bg * HWHW + i0) * 32 + u]);
  if (t < JD) { sv0[t] = vn0[bg * JD + t]; sv1[t] = vn1[bg * JD + t]; }

  // ---- per-lane resident weights ----
  float w00r[8], w01r[8], b0r[8];
#pragma unroll
  for (int j = 0; j < 8; ++j) {
    int k = quad * 8 + j;
    w00r[j] = w0[k]; w01r[j] = w0[32 + k]; b0r[j] = b0[k];
  }
  short8 w1f0, w1f1;   // B-frags of W1 (K=32, two N-halves)
#pragma unroll
  for (int j = 0; j < 8; ++j) {
    int k = quad * 8 + j;
    w1f0[j] = (short)f2bf(w1[k * 32 + lam]);
    w1f1[j] = (short)f2bf(w1[k * 32 + 16 + lam]);
  }
  float b1n0 = b1[lam], b1n1 = b1[16 + lam];
  float w2n0 = w2[lam], w2n1 = w2[16 + lam];
  float b2s = b2[0];

  __syncthreads();   // B1

  // ---- P1: sim = q·kT (scaled); waves split 2 M-tiles x 9 N-tiles ----
  const float scale = 0.17677669529663687f;   // 32^-0.5
  {
    int m = w >> 1;
    short8 aq = *(const short8*)(qbf + (m * 16 + lam) * 32 + quad * 8);
    int jt0 = (w & 1) ? 5 : 0, jt1 = (w & 1) ? 9 : 5;
#pragma unroll 1
    for (int jt = jt0; jt < jt1; ++jt) {
      short8 bk = *(const short8*)(kbf + (jt * 16 + lam) * 32 + quad * 8);
      f32x4 acc = {0.f, 0.f, 0.f, 0.f};
      acc = __builtin_amdgcn_mfma_f32_16x16x32_bf16(aq, bk, acc, 0, 0, 0);
#pragma unroll
      for (int r = 0; r < 4; ++r)
        Ls[(m * 16 + quad * 4 + r) * LSP + jt * 16 + lam] = acc[r] * scale;
    }
  }
  __syncthreads();   // B2

  // ---- P2: CPB bias; wave owns 8 rows => 18 sub-iters of 64 pairs ----
  f32x4 zA = {b1n0, b1n0, b1n0, b1n0};   // fold b1 into MFMA C-init
  f32x4 zB = {b1n1, b1n1, b1n1, b1n1};
#pragma unroll 1
  for (int s = 0; s < 18; ++s) {
    int P0 = s * 64 + lane;
    int ii0 = P0 / 144, jj0 = P0 - ii0 * 144;
    int ig = i0 + w * 8 + ii0;
    int iy = ig / 48, ix = ig - iy * 48;
    float p0 = (float)ix * (2.f / 47.f) - 1.f - sv0[jj0];
    float p1 = (float)iy * (2.f / 47.f) - 1.f - sv1[jj0];
    float s0f = copysignf(__logf(1.f + fabsf(p0)), p0);
    float s1f = copysignf(__logf(1.f + fabsf(p1)), p1);
    f32x4 dA[4], dB[4];
#pragma unroll
    for (int mt = 0; mt < 4; ++mt) {
      float s0 = __shfl(s0f, mt * 16 + lam, 64);
      float s1 = __shfl(s1f, mt * 16 + lam, 64);
      float h[8];
#pragma unroll
      for (int j = 0; j < 8; ++j)
        h[j] = fmaxf(fmaf(s0, w00r[j], fmaf(s1, w01r[j], b0r[j])), 0.f);
      union { uint u[4]; short8 s8; } cvt;   // truncating f32->bf16 pack via v_perm
#pragma unroll
      for (int j = 0; j < 4; ++j)
        cvt.u[j] = __builtin_amdgcn_perm(__float_as_uint(h[2 * j + 1]),
                                         __float_as_uint(h[2 * j]), 0x07060302);
      dA[mt] = __builtin_amdgcn_mfma_f32_16x16x32_bf16(cvt.s8, w1f0, zA, 0, 0, 0);
      dB[mt] = __builtin_amdgcn_mfma_f32_16x16x32_bf16(cvt.s8, w1f1, zB, 0, 0, 0);
    }
    float v[16];
#pragma unroll
    for (int mt = 0; mt < 4; ++mt)
#pragma unroll
      for (int r = 0; r < 4; ++r)
        v[mt * 4 + r] = fmaf(fmaxf(dB[mt][r], 0.f), w2n1,
                             fmaxf(dA[mt][r], 0.f) * w2n0);
#define RSTEP(K, HALF)                                                        \
    { bool hi = (lam & K) != 0;                                               \
      _Pragma("unroll")                                                       \
      for (int i2 = 0; i2 < HALF; ++i2) {                                     \
        float send = hi ? v[i2] : v[i2 + HALF];                               \
        float recv = __shfl_xor(send, K, 64);                                 \
        v[i2] = (hi ? v[i2 + HALF] : v[i2]) + recv;                           \
      } }
    RSTEP(8, 8) RSTEP(4, 4) RSTEP(2, 2) RSTEP(1, 1)
#undef RSTEP
    float biasv = v[0] + b2s;
    int pair64 = ((lam >> 2) << 4) + (quad << 2) + (lam & 3);
    int P = s * 64 + pair64;
    int ii = P / 144, jj = P - ii * 144;
    Ls[(w * 8 + ii) * LSP + jj] += biasv;
  }
  __syncthreads();   // B3

  // ---- stage vT as bf16 (overlaps kbf, now dead); zero K-pad ----
  for (int u = t; u < 32 * JD; u += 256) {
    int d = u / JD, j = u - d * JD;
    vbfT[d * 160 + j] = f2bf(vtT[bg * 4608 + u]);
  }
  for (int u = t; u < 512; u += 256)
    vbfT[(u >> 4) * 160 + 144 + (u & 15)] = 0;

  // ---- P3: softmax per row; P packed bf16 in-place (upper half of row) ----
#pragma unroll 1
  for (int rr = 0; rr < 8; ++rr) {
    int row = w * 8 + rr;
    const float* Lp = Ls + row * LSP;
    float l0 = Lp[lane], l1 = Lp[64 + lane];
    float l2 = (lane < 16) ? Lp[128 + lane] : -INFINITY;
    float m = fmaxf(fmaxf(l0, l1), l2);
#pragma unroll
    for (int k = 32; k >= 1; k >>= 1) m = fmaxf(m, __shfl_xor(m, k, 64));
    float e0 = __expf(l0 - m), e1 = __expf(l1 - m);
    float e2 = (lane < 16) ? __expf(l2 - m) : 0.f;
    float sum = e0 + e1 + e2;
#pragma unroll
    for (int k = 32; k >= 1; k >>= 1) sum += __shfl_xor(sum, k, 64);
    float inv = 1.f / sum;
    ushort* pb = (ushort*)(Lp + 64);
    pb[lane] = f2bf(e0 * inv);
    pb[64 + lane] = f2bf(e1 * inv);
    if (lane < 32) pb[128 + lane] = (lane < 16) ? f2bf(e2 * inv) : (ushort)0;
  }
  __syncthreads();   // B4

  // ---- P4: O = P·v; waves split 2 M-tiles x 2 col-halves ----
  {
    int m = w >> 1, half = w & 1;
    f32x4 o = {0.f, 0.f, 0.f, 0.f};
    const ushort* pb = (const ushort*)(Ls + (m * 16 + lam) * LSP + 64);
    const ushort* vb = vbfT + (half * 16 + lam) * 160;
#pragma unroll
    for (int kb = 0; kb < 5; ++kb) {
      short8 ap = *(const short8*)(pb + kb * 32 + quad * 8);
      short8 bv = *(const short8*)(vb + kb * 32 + quad * 8);
      o = __builtin_amdgcn_mfma_f32_16x16x32_bf16(ap, bv, o, 0, 0, 0);
    }
#pragma unroll
    for (int r = 0; r < 4; ++r) {
      int ig = i0 + m * 16 + quad * 4 + r;
      outh[((long)b * HWHW + ig) * 128 + g * 32 + half * 16 + lam] = o[r];
    }
  }
}

// grid (36 hw-chunks, 2 b, 4 o-chunks): wave computes 8 o over 64 hw.
__global__ __launch_bounds__(256) void out_kernel(
    const float* __restrict__ outh, const float* __restrict__ wo,
    const float* __restrict__ bo, const float* __restrict__ x,
    const float* __restrict__ gamma, float* __restrict__ out) {
  __shared__ float tile[64 * 129];   // +1 pad: row-read bank-conflict-free
  int b = blockIdx.y;
  int hw0 = blockIdx.x * 64;
  int oc0 = blockIdx.z * 32;
  int t = threadIdx.x;
  int wid = t >> 6, lane = t & 63;
  for (int u = t; u < 2048; u += 256) {
    int r = u >> 5, c4 = (u & 31) * 4;
    const float4 v = *(const float4*)(outh + (b * HWHW + hw0 + r) * 128 + c4);
    float* dst = tile + r * 129 + c4;
    dst[0] = v.x; dst[1] = v.y; dst[2] = v.z; dst[3] = v.w;
  }
  __syncthreads();
  float acc[8];
#pragma unroll
  for (int o = 0; o < 8; ++o) acc[o] = 0.f;
  const float* wop = wo + (oc0 + wid * 8) * 128;   // uniform per wave -> scalar
  const float* row = tile + lane * 129;
#pragma unroll 1
  for (int c4 = 0; c4 < 128; c4 += 4) {
    float v0 = row[c4], v1 = row[c4 + 1], v2 = row[c4 + 2], v3 = row[c4 + 3];
#pragma unroll
    for (int o = 0; o < 8; ++o) {
      acc[o] += wop[o * 128 + c4] * v0 + wop[o * 128 + c4 + 1] * v1
              + wop[o * 128 + c4 + 2] * v2 + wop[o * 128 + c4 + 3] * v3;
    }
  }
  float gm = gamma[0];
  float* out0 = out;
  float* out1 = out + 2 * 128 * HWHW;
#pragma unroll
  for (int o = 0; o < 8; ++o) {
    int oc = oc0 + wid * 8 + o;
    int idx = (b * 128 + oc) * HWHW + hw0 + lane;
    float a = acc[o] + bo[oc];
    out1[idx] = a;
    out0[idx] = fmaf(gm, a, x[idx]);
  }
}

extern "C" void kernel_launch(void* const* d_in, const int* in_sizes, int n_in,
                              void* d_out, int out_size, void* d_ws, size_t ws_size,
                              hipStream_t stream) {
  const float* x     = (const float*)d_in[0];
  const float* gamma = (const float*)d_in[1];
  const float* wq    = (const float*)d_in[2];
  const float* wk    = (const float*)d_in[3];
  const float* wv    = (const float*)d_in[4];
  const float* wo    = (const float*)d_in[5];
  const float* bo    = (const float*)d_in[6];
  const float* wdw   = (const float*)d_in[7];
  const float* bdw   = (const float*)d_in[8];
  const float* wproj = (const float*)d_in[9];
  const float* cw0   = (const float*)d_in[10];
  const float* cb0   = (const float*)d_in[11];
  const float* cw1   = (const float*)d_in[12];
  const float* cb1   = (const float*)d_in[13];
  const float* cw2   = (const float*)d_in[14];
  const float* cb2   = (const float*)d_in[15];
  float* ws   = (float*)d_ws;
  float* q    = ws;
  float* qt   = ws + 589824;
  float* vn0  = ws + 1179648;
  float* vn1  = ws + 1180800;
  float* px   = ws + 1181952;
  float* py   = ws + 1183104;
  float* kt   = ws + 1184256;
  float* vtT  = ws + 1221120;
  float* outh = ws + 1257984;
  float* out  = (float*)d_out;

  qproj_kernel<<<dim3(9, 4, 8), 256, 0, stream>>>(x, wq, q, qt);
  offset_kernel<<<dim3(12, 8), 384, 0, stream>>>(q, wdw, bdw, wproj, vn0, vn1, px, py);
  kv_kernel<<<dim3(9, 8), 256, 0, stream>>>(x, wk, wv, px, py, kt, vtT);
  attn_fused_kernel<<<dim3(72, 8), 256, 0, stream>>>(qt, kt, vtT, vn0, vn1,
                                                     cw0, cb0, cw1, cb1, cw2, cb2, outh);
  out_kernel<<<dim3(36, 2, 4), 256, 0, stream>>>(outh, wo, bo, x, gamma, out);
}

// Round 5
// 153.097 us; speedup vs baseline: 3.7374x; 1.1475x over previous
//
#include <hip/hip_runtime.h>
#include <math.h>

// dims
#define HWHW 2304   // 48*48
#define JD   144    // 12*12
#define LSP  148    // Ls row stride in dwords

typedef __attribute__((ext_vector_type(8))) short short8;
typedef __attribute__((ext_vector_type(4))) float f32x4;

__device__ inline ushort f2bf(float f) {
  uint u = __float_as_uint(f);
  u += 0x7fffu + ((u >> 16) & 1u);   // RNE
  return (ushort)(u >> 16);
}
__device__ inline float bf2f(ushort s) { return __uint_as_float((uint)s << 16); }

// ws layout (byte offsets)
// qt_bf  [8][2304][32] u16  @ 0         (1179648 B)
// vn0    [8][144] f32       @ 1179648
// vn1    [8][144] f32       @ 1184256
// kt_bf  [8][144][32] u16   @ 1188864   (73728 B)
// vtT_bf [8][32][160] u16   @ 1262592   (81920 B, j=144..159 zeroed)
// outh   [2][2304][128] f32 @ 1344512   (end 3703808 B)

// grid (9 hw-chunks, 4 o-chunks, 8 bg): thread holds 32 x-ch in regs, computes 8 o -> bf16 qt.
__global__ __launch_bounds__(256) void qproj_kernel(
    const float* __restrict__ x, const float* __restrict__ wq,
    ushort* __restrict__ qt) {
  int hw = blockIdx.x * 256 + threadIdx.x;
  int o0 = blockIdx.y * 8, bg = blockIdx.z;
  int b = bg >> 2, g = bg & 3;
  const float* xp = x + (b * 128 + g * 32) * HWHW + hw;
  float xv[32];
#pragma unroll
  for (int c = 0; c < 32; ++c) xv[c] = xp[c * HWHW];
  uint p[4];
#pragma unroll
  for (int oo = 0; oo < 8; oo += 2) {
    const float* w0r = wq + (g * 32 + o0 + oo) * 32;       // uniform -> scalar
    const float* w1r = wq + (g * 32 + o0 + oo + 1) * 32;
    float a0 = 0.f, a1 = 0.f;
#pragma unroll
    for (int c = 0; c < 32; ++c) { a0 += w0r[c] * xv[c]; a1 += w1r[c] * xv[c]; }
    p[oo >> 1] = (uint)f2bf(a0) | ((uint)f2bf(a1) << 16);
  }
  *(uint4*)(qt + ((long)bg * HWHW + hw) * 32 + o0) = make_uint4(p[0], p[1], p[2], p[3]);
}

// grid (12 hd, 8 bg), 384 thr. Fused: depthwise conv -> GELU -> proj -> tanh ->
// grid coords -> bilinear sample -> k/v proj (bf16 out).
__global__ __launch_bounds__(384) void offset_kv_kernel(
    const ushort* __restrict__ qt, const float* __restrict__ wdw,
    const float* __restrict__ bdw, const float* __restrict__ wproj,
    const float* __restrict__ x, const float* __restrict__ wk,
    const float* __restrict__ wv,
    float* __restrict__ vn0, float* __restrict__ vn1,
    ushort* __restrict__ ktb, ushort* __restrict__ vtb) {
  __shared__ float qs[288][32];      // [ry*48+col][c] — conflict-free both ways
  __shared__ float wdws[36][32];     // [k][c]
  __shared__ float wkl[32][33], wvl[32][33];   // [d][c]
  __shared__ float kvs[32][13];      // [c][j] (+pad)
  __shared__ float spx[12], spy[12];
  int hd = blockIdx.x, bg = blockIdx.y, b = bg >> 2, g = bg & 3;
  int t = threadIdx.x;
  for (int u = t; u < 9216; u += 384) {
    int r = u >> 5, c = u & 31;
    int ry = r / 48, col = r - ry * 48;
    int hy = hd * 4 - 1 + ry;
    float v = 0.f;
    if (hy >= 0 && hy < 48)
      v = bf2f(qt[((long)bg * HWHW + hy * 48 + col) * 32 + c]);
    qs[r][c] = v;
  }
  for (int u = t; u < 1152; u += 384) wdws[u >> 5][u & 31] = wdw[(u & 31) * 36 + (u >> 5)];
  for (int u = t; u < 1024; u += 384) {
    int d = u >> 5, c = u & 31;
    wkl[d][c] = wk[g * 1024 + u];
    wvl[d][c] = wv[g * 1024 + u];
  }
  __syncthreads();
  {
    int wd = t >> 5, c = t & 31;
    float s = 0.f;
#pragma unroll
    for (int ky = 0; ky < 6; ++ky) {
#pragma unroll
      for (int kx = 0; kx < 6; ++kx) {
        int wx = wd * 4 - 1 + kx;
        if (wx >= 0 && wx < 48)
          s += wdws[ky * 6 + kx][c] * qs[ky * 48 + wx][c];
      }
    }
    s += bdw[c];
    s = 0.5f * s * (1.f + erff(s * 0.70710678118654752f));  // exact GELU
    float g0 = wproj[c] * s;
    float g1 = wproj[32 + c] * s;
#pragma unroll
    for (int k = 16; k >= 1; k >>= 1) {
      g0 += __shfl_xor(g0, k, 64);
      g1 += __shfl_xor(g1, k, 64);
    }
    if (c == 0) {
      float off0 = tanhf(g0) * 4.f;
      float off1 = tanhf(g1) * 4.f;
      float n0 = 2.f * ((float)wd + off0) / 11.f - 1.f;
      float n1 = 2.f * ((float)hd + off1) / 11.f - 1.f;
      int idx = bg * JD + hd * 12 + wd;
      vn0[idx] = n0;
      vn1[idx] = n1;
      spx[wd] = ((n0 + 1.f) * 48.f - 1.f) * 0.5f;
      spy[wd] = ((n1 + 1.f) * 48.f - 1.f) * 0.5f;
    }
  }
  __syncthreads();
  {
    int j = t >> 5, c = t & 31;
    float fx = spx[j], fy = spy[j];
    float x0 = floorf(fx), y0 = floorf(fy);
    float wx = fx - x0, wy = fy - y0;
    int xi = (int)x0, yi = (int)y0;
    const float* xp = x + (b * 128 + g * 32 + c) * HWHW;
    float v00 = 0.f, v10 = 0.f, v01 = 0.f, v11 = 0.f;
    bool okx0 = (xi >= 0) & (xi < 48), okx1 = (xi + 1 >= 0) & (xi + 1 < 48);
    if (yi >= 0 && yi < 48) {
      if (okx0) v00 = xp[yi * 48 + xi];
      if (okx1) v10 = xp[yi * 48 + xi + 1];
    }
    if (yi + 1 >= 0 && yi + 1 < 48) {
      if (okx0) v01 = xp[(yi + 1) * 48 + xi];
      if (okx1) v11 = xp[(yi + 1) * 48 + xi + 1];
    }
    kvs[c][j] = v00 * (1.f - wx) * (1.f - wy) + v10 * wx * (1.f - wy)
              + v01 * (1.f - wx) * wy + v11 * wx * wy;
  }
  __syncthreads();
  {
    int j = t >> 5, d = t & 31;
    float ak = 0.f, av = 0.f;
#pragma unroll
    for (int c = 0; c < 32; ++c) {
      float val = kvs[c][j];
      ak += wkl[d][c] * val;
      av += wvl[d][c] * val;
    }
    int jg = hd * 12 + j;
    ktb[bg * 4608 + jg * 32 + d] = f2bf(ak);
    vtb[bg * 5120 + d * 160 + jg] = f2bf(av);
  }
  if (hd == 0) {   // zero the v K-pad for this bg (j = 144..159)
    for (int u = t; u < 512; u += 384)
      vtb[bg * 5120 + (u >> 4) * 160 + 144 + (u & 15)] = 0;
  }
}

// Fused attention: block = (bg, 16 q-rows), 256 thr = 4 waves.
__global__ __launch_bounds__(256) void attn_fused_kernel(
    const ushort* __restrict__ qt, const ushort* __restrict__ ktb,
    const ushort* __restrict__ vtb,
    const float* __restrict__ vn0, const float* __restrict__ vn1,
    const float* __restrict__ w0, const float* __restrict__ b0,
    const float* __restrict__ w1, const float* __restrict__ b1,
    const float* __restrict__ w2, const float* __restrict__ b2,
    float* __restrict__ outh) {
  __shared__ __align__(16) char smem[21888];
  float* Ls = (float*)smem;                    // [16][LSP] fp32; P bf16 at dwords 64..143
  ushort* kbf = (ushort*)(smem + 9472);        // [144][32] bf16 (P1)
  ushort* vbfT = (ushort*)(smem + 9472);       // [32][160] bf16 (P4), overlaps kbf
  ushort* qbf = (ushort*)(smem + 19712);       // [16][32] bf16
  float* sv0 = (float*)(smem + 20736);         // [144]
  float* sv1 = (float*)(smem + 21312);         // [144]

  int bg = blockIdx.y, b = bg >> 2, g = bg & 3;
  int i0 = blockIdx.x * 16;
  int t = threadIdx.x;
  int w = t >> 6, lane = t & 63;
  int lam = lane & 15, quad = lane >> 4;

  // ---- stage (pure dword copies — data is already bf16) ----
  {
    const uint* src = (const uint*)(ktb + bg * 4608);
    uint* dst = (uint*)kbf;
    for (int u = t; u < 2304; u += 256) dst[u] = src[u];
    ((uint*)qbf)[t] = ((const uint*)(qt + ((long)bg * HWHW + i0) * 32))[t];
  }
  if (t < JD) { sv0[t] = vn0[bg * JD + t]; sv1[t] = vn1[bg * JD + t]; }

  // ---- per-lane resident weights ----
  float w00r[8], w01r[8], b0r[8];
#pragma unroll
  for (int j = 0; j < 8; ++j) {
    int k = quad * 8 + j;
    w00r[j] = w0[k]; w01r[j] = w0[32 + k]; b0r[j] = b0[k];
  }
  short8 w1f0, w1f1;   // W1^T A-frags (m=n-out, k=c-in), two 16-row tiles
#pragma unroll
  for (int j = 0; j < 8; ++j) {
    int k = quad * 8 + j;
    w1f0[j] = (short)f2bf(w1[k * 32 + lam]);
    w1f1[j] = (short)f2bf(w1[k * 32 + 16 + lam]);
  }
  f32x4 zA, zB;       // b1 folded into C-init (n = quad*4+r / 16+quad*4+r)
  float w2r[8];
#pragma unroll
  for (int r = 0; r < 4; ++r) {
    zA[r] = b1[quad * 4 + r];
    zB[r] = b1[16 + quad * 4 + r];
    w2r[r] = w2[quad * 4 + r];
    w2r[4 + r] = w2[16 + quad * 4 + r];
  }
  float b2s = b2[0];

  __syncthreads();   // B1

  // ---- P1: sim = q·kT (scaled); 9 N-tiles round-robin over 4 waves ----
  const float scale = 0.17677669529663687f;   // 32^-0.5
  {
    short8 aq = *(const short8*)(qbf + lam * 32 + quad * 8);
#pragma unroll 1
    for (int jt = w; jt < 9; jt += 4) {
      short8 bk = *(const short8*)(kbf + (jt * 16 + lam) * 32 + quad * 8);
      f32x4 acc = {0.f, 0.f, 0.f, 0.f};
      acc = __builtin_amdgcn_mfma_f32_16x16x32_bf16(aq, bk, acc, 0, 0, 0);
#pragma unroll
      for (int r = 0; r < 4; ++r)
        Ls[(quad * 4 + r) * LSP + jt * 16 + lam] = acc[r] * scale;
    }
  }
  __syncthreads();   // B2

  // ---- P2: CPB bias; wave owns 4 rows => 9 sub-iters of 64 pairs.
  // Transposed middle layer: D = W1^T·h1^T = h2^T, so lane holds its own
  // pair's h2 slice in C-regs; reduce = in-lane fma chain + 2 shfl_xor.
#pragma unroll 1
  for (int s = 0; s < 9; ++s) {
    int P = s * 64 + lane;
    int ii = P / 144, jj = P - ii * 144;
    int ig = i0 + w * 4 + ii;
    int iy = ig / 48, ix = ig - iy * 48;
    float p0 = (float)ix * (2.f / 47.f) - 1.f - sv0[jj];
    float p1 = (float)iy * (2.f / 47.f) - 1.f - sv1[jj];
    float s0f = copysignf(__logf(1.f + fabsf(p0)), p0);
    float s1f = copysignf(__logf(1.f + fabsf(p1)), p1);
    float bm[4];
#pragma unroll
    for (int mt = 0; mt < 4; ++mt) {
      float s0 = __shfl(s0f, mt * 16 + lam, 64);
      float s1 = __shfl(s1f, mt * 16 + lam, 64);
      float h[8];
#pragma unroll
      for (int j = 0; j < 8; ++j)
        h[j] = fmaxf(fmaf(s0, w00r[j], fmaf(s1, w01r[j], b0r[j])), 0.f);
      union { uint u[4]; short8 s8; } cvt;   // truncating f32->bf16 pack
#pragma unroll
      for (int j = 0; j < 4; ++j)
        cvt.u[j] = __builtin_amdgcn_perm(__float_as_uint(h[2 * j + 1]),
                                         __float_as_uint(h[2 * j]), 0x07060302);
      f32x4 dA = __builtin_amdgcn_mfma_f32_16x16x32_bf16(w1f0, cvt.s8, zA, 0, 0, 0);
      f32x4 dB = __builtin_amdgcn_mfma_f32_16x16x32_bf16(w1f1, cvt.s8, zB, 0, 0, 0);
      float acc = 0.f;
#pragma unroll
      for (int r = 0; r < 4; ++r) {
        acc = fmaf(fmaxf(dA[r], 0.f), w2r[r], acc);
        acc = fmaf(fmaxf(dB[r], 0.f), w2r[4 + r], acc);
      }
      acc += __shfl_xor(acc, 16, 64);
      acc += __shfl_xor(acc, 32, 64);
      bm[mt] = acc;
    }
    // lane (lam,quad) owns pair quad*16+lam == lane => P = s*64+lane (as above)
    float biasv = (quad == 0 ? bm[0] : quad == 1 ? bm[1] : quad == 2 ? bm[2] : bm[3]) + b2s;
    Ls[(w * 4 + ii) * LSP + jj] += biasv;
  }
  __syncthreads();   // B3

  // ---- stage vT bf16 (overlaps kbf, dead after P1); pad pre-zeroed in global ----
  {
    const uint* src = (const uint*)(vtb + bg * 5120);
    uint* dst = (uint*)vbfT;
    for (int u = t; u < 2560; u += 256) dst[u] = src[u];
  }

  // ---- P3: softmax per row (wave owns 4 rows); P packed bf16 in-place ----
#pragma unroll 1
  for (int rr = 0; rr < 4; ++rr) {
    int row = w * 4 + rr;
    const float* Lp = Ls + row * LSP;
    float l0 = Lp[lane], l1 = Lp[64 + lane];
    float l2 = (lane < 16) ? Lp[128 + lane] : -INFINITY;
    float m = fmaxf(fmaxf(l0, l1), l2);
#pragma unroll
    for (int k = 32; k >= 1; k >>= 1) m = fmaxf(m, __shfl_xor(m, k, 64));
    float e0 = __expf(l0 - m), e1 = __expf(l1 - m);
    float e2 = (lane < 16) ? __expf(l2 - m) : 0.f;
    float sum = e0 + e1 + e2;
#pragma unroll
    for (int k = 32; k >= 1; k >>= 1) sum += __shfl_xor(sum, k, 64);
    float inv = 1.f / sum;
    ushort* pb = (ushort*)(Lp + 64);
    pb[lane] = f2bf(e0 * inv);
    pb[64 + lane] = f2bf(e1 * inv);
    if (lane < 32) pb[128 + lane] = (lane < 16) ? f2bf(e2 * inv) : (ushort)0;
  }
  __syncthreads();   // B4

  // ---- P4: O = P·v (K=160, zero-padded); waves 0,1 take the 2 col-halves ----
  if (w < 2) {
    f32x4 o = {0.f, 0.f, 0.f, 0.f};
    const ushort* pb = (const ushort*)(Ls + lam * LSP + 64);
    const ushort* vb = vbfT + (w * 16 + lam) * 160;
#pragma unroll
    for (int kb = 0; kb < 5; ++kb) {
      short8 ap = *(const short8*)(pb + kb * 32 + quad * 8);
      short8 bv = *(const short8*)(vb + kb * 32 + quad * 8);
      o = __builtin_amdgcn_mfma_f32_16x16x32_bf16(ap, bv, o, 0, 0, 0);
    }
#pragma unroll
    for (int r = 0; r < 4; ++r) {
      int ig = i0 + quad * 4 + r;
      outh[((long)b * HWHW + ig) * 128 + g * 32 + w * 16 + lam] = o[r];
    }
  }
}

// grid (36 hw-chunks, 2 b, 4 o-chunks): wave computes 8 o over 64 hw.
__global__ __launch_bounds__(256) void out_kernel(
    const float* __restrict__ outh, const float* __restrict__ wo,
    const float* __restrict__ bo, const float* __restrict__ x,
    const float* __restrict__ gamma, float* __restrict__ out) {
  __shared__ float tile[64 * 129];   // +1 pad: row-read bank-conflict-free
  int b = blockIdx.y;
  int hw0 = blockIdx.x * 64;
  int oc0 = blockIdx.z * 32;
  int t = threadIdx.x;
  int wid = t >> 6, lane = t & 63;
  for (int u = t; u < 2048; u += 256) {
    int r = u >> 5, c4 = (u & 31) * 4;
    const float4 v = *(const float4*)(outh + (b * HWHW + hw0 + r) * 128 + c4);
    float* dst = tile + r * 129 + c4;
    dst[0] = v.x; dst[1] = v.y; dst[2] = v.z; dst[3] = v.w;
  }
  __syncthreads();
  float acc[8];
#pragma unroll
  for (int o = 0; o < 8; ++o) acc[o] = 0.f;
  const float* wop = wo + (oc0 + wid * 8) * 128;   // uniform per wave -> scalar
  const float* row = tile + lane * 129;
#pragma unroll 1
  for (int c4 = 0; c4 < 128; c4 += 4) {
    float v0 = row[c4], v1 = row[c4 + 1], v2 = row[c4 + 2], v3 = row[c4 + 3];
#pragma unroll
    for (int o = 0; o < 8; ++o) {
      acc[o] += wop[o * 128 + c4] * v0 + wop[o * 128 + c4 + 1] * v1
              + wop[o * 128 + c4 + 2] * v2 + wop[o * 128 + c4 + 3] * v3;
    }
  }
  float gm = gamma[0];
  float* out0 = out;
  float* out1 = out + 2 * 128 * HWHW;
#pragma unroll
  for (int o = 0; o < 8; ++o) {
    int oc = oc0 + wid * 8 + o;
    int idx = (b * 128 + oc) * HWHW + hw0 + lane;
    float a = acc[o] + bo[oc];
    out1[idx] = a;
    out0[idx] = fmaf(gm, a, x[idx]);
  }
}

extern "C" void kernel_launch(void* const* d_in, const int* in_sizes, int n_in,
                              void* d_out, int out_size, void* d_ws, size_t ws_size,
                              hipStream_t stream) {
  const float* x     = (const float*)d_in[0];
  const float* gamma = (const float*)d_in[1];
  const float* wq    = (const float*)d_in[2];
  const float* wk    = (const float*)d_in[3];
  const float* wv    = (const float*)d_in[4];
  const float* wo    = (const float*)d_in[5];
  const float* bo    = (const float*)d_in[6];
  const float* wdw   = (const float*)d_in[7];
  const float* bdw   = (const float*)d_in[8];
  const float* wproj = (const float*)d_in[9];
  const float* cw0   = (const float*)d_in[10];
  const float* cb0   = (const float*)d_in[11];
  const float* cw1   = (const float*)d_in[12];
  const float* cb1   = (const float*)d_in[13];
  const float* cw2   = (const float*)d_in[14];
  const float* cb2   = (const float*)d_in[15];
  char* wsb = (char*)d_ws;
  ushort* qt  = (ushort*)wsb;
  float* vn0  = (float*)(wsb + 1179648);
  float* vn1  = (float*)(wsb + 1184256);
  ushort* ktb = (ushort*)(wsb + 1188864);
  ushort* vtb = (ushort*)(wsb + 1262592);
  float* outh = (float*)(wsb + 1344512);
  float* out  = (float*)d_out;

  qproj_kernel<<<dim3(9, 4, 8), 256, 0, stream>>>(x, wq, qt);
  offset_kv_kernel<<<dim3(12, 8), 384, 0, stream>>>(qt, wdw, bdw, wproj, x, wk, wv,
                                                    vn0, vn1, ktb, vtb);
  attn_fused_kernel<<<dim3(144, 8), 256, 0, stream>>>(qt, ktb, vtb, vn0, vn1,
                                                      cw0, cb0, cw1, cb1, cw2, cb2, outh);
  out_kernel<<<dim3(36, 2, 4), 256, 0, stream>>>(outh, wo, bo, x, gamma, out);
}

// Round 6
// 138.007 us; speedup vs baseline: 4.1461x; 1.1093x over previous
//
#include <hip/hip_runtime.h>
#include <math.h>

// dims
#define HWHW 2304   // 48*48
#define JD   144    // 12*12
#define LSP  148    // Ls row stride in dwords

typedef __attribute__((ext_vector_type(8))) short short8;
typedef __attribute__((ext_vector_type(4))) float f32x4;

__device__ inline ushort f2bf(float f) {
  uint u = __float_as_uint(f);
  u += 0x7fffu + ((u >> 16) & 1u);   // RNE
  return (ushort)(u >> 16);
}
__device__ inline float bf2f(ushort s) { return __uint_as_float((uint)s << 16); }

// ws layout (byte offsets)
// qt_bf   [8][2304][32] u16  @ 0         (1179648 B)
// vn0     [8][144] f32       @ 1179648
// vn1     [8][144] f32       @ 1184256
// kt_bf   [8][144][32] u16   @ 1188864   (73728 B)
// vtT_bf  [8][32][160] u16   @ 1262592   (81920 B, j=144..159 zeroed)
// outh_bf [2][2304][128] u16 @ 1344512   (1179648 B, end 2524160 B)

// grid (9 hw-chunks, 4 o-chunks, 8 bg): thread holds 32 x-ch in regs, computes 8 o -> bf16 qt.
__global__ __launch_bounds__(256) void qproj_kernel(
    const float* __restrict__ x, const float* __restrict__ wq,
    ushort* __restrict__ qt) {
  int hw = blockIdx.x * 256 + threadIdx.x;
  int o0 = blockIdx.y * 8, bg = blockIdx.z;
  int b = bg >> 2, g = bg & 3;
  const float* xp = x + (b * 128 + g * 32) * HWHW + hw;
  float xv[32];
#pragma unroll
  for (int c = 0; c < 32; ++c) xv[c] = xp[c * HWHW];
  uint p[4];
#pragma unroll
  for (int oo = 0; oo < 8; oo += 2) {
    const float* w0r = wq + (g * 32 + o0 + oo) * 32;       // uniform -> scalar
    const float* w1r = wq + (g * 32 + o0 + oo + 1) * 32;
    float a0 = 0.f, a1 = 0.f;
#pragma unroll
    for (int c = 0; c < 32; ++c) { a0 += w0r[c] * xv[c]; a1 += w1r[c] * xv[c]; }
    p[oo >> 1] = (uint)f2bf(a0) | ((uint)f2bf(a1) << 16);
  }
  *(uint4*)(qt + ((long)bg * HWHW + hw) * 32 + o0) = make_uint4(p[0], p[1], p[2], p[3]);
}

// grid (12 hd, 8 bg), 384 thr. Fused: depthwise conv -> GELU -> proj -> tanh ->
// grid coords -> bilinear sample -> k/v proj (bf16 out).
__global__ __launch_bounds__(384) void offset_kv_kernel(
    const ushort* __restrict__ qt, const float* __restrict__ wdw,
    const float* __restrict__ bdw, const float* __restrict__ wproj,
    const float* __restrict__ x, const float* __restrict__ wk,
    const float* __restrict__ wv,
    float* __restrict__ vn0, float* __restrict__ vn1,
    ushort* __restrict__ ktb, ushort* __restrict__ vtb) {
  __shared__ float qs[288][32];      // [ry*48+col][c] — conflict-free both ways
  __shared__ float wdws[36][32];     // [k][c]
  __shared__ float wkl[32][33], wvl[32][33];   // [d][c]
  __shared__ float kvs[32][13];      // [c][j] (+pad)
  __shared__ float spx[12], spy[12];
  int hd = blockIdx.x, bg = blockIdx.y, b = bg >> 2, g = bg & 3;
  int t = threadIdx.x;
  for (int u = t; u < 4608; u += 384) {   // uint loads: 2 channels per lane
    int r = u >> 4, c2 = u & 15;
    int ry = r / 48, col = r - ry * 48;
    int hy = hd * 4 - 1 + ry;
    uint v = 0;
    if (hy >= 0 && hy < 48)
      v = ((const uint*)qt)[((long)bg * HWHW + hy * 48 + col) * 16 + c2];
    qs[r][c2 * 2] = bf2f((ushort)v);
    qs[r][c2 * 2 + 1] = bf2f((ushort)(v >> 16));
  }
  for (int u = t; u < 1152; u += 384) wdws[u >> 5][u & 31] = wdw[(u & 31) * 36 + (u >> 5)];
  for (int u = t; u < 1024; u += 384) {
    int d = u >> 5, c = u & 31;
    wkl[d][c] = wk[g * 1024 + u];
    wvl[d][c] = wv[g * 1024 + u];
  }
  __syncthreads();
  {
    int wd = t >> 5, c = t & 31;
    float s = 0.f;
#pragma unroll
    for (int ky = 0; ky < 6; ++ky) {
#pragma unroll
      for (int kx = 0; kx < 6; ++kx) {
        int wx = wd * 4 - 1 + kx;
        if (wx >= 0 && wx < 48)
          s += wdws[ky * 6 + kx][c] * qs[ky * 48 + wx][c];
      }
    }
    s += bdw[c];
    s = 0.5f * s * (1.f + erff(s * 0.70710678118654752f));  // exact GELU
    float g0 = wproj[c] * s;
    float g1 = wproj[32 + c] * s;
#pragma unroll
    for (int k = 16; k >= 1; k >>= 1) {
      g0 += __shfl_xor(g0, k, 64);
      g1 += __shfl_xor(g1, k, 64);
    }
    if (c == 0) {
      float off0 = tanhf(g0) * 4.f;
      float off1 = tanhf(g1) * 4.f;
      float n0 = 2.f * ((float)wd + off0) / 11.f - 1.f;
      float n1 = 2.f * ((float)hd + off1) / 11.f - 1.f;
      int idx = bg * JD + hd * 12 + wd;
      vn0[idx] = n0;
      vn1[idx] = n1;
      spx[wd] = ((n0 + 1.f) * 48.f - 1.f) * 0.5f;
      spy[wd] = ((n1 + 1.f) * 48.f - 1.f) * 0.5f;
    }
  }
  __syncthreads();
  {
    int j = t >> 5, c = t & 31;
    float fx = spx[j], fy = spy[j];
    float x0 = floorf(fx), y0 = floorf(fy);
    float wx = fx - x0, wy = fy - y0;
    int xi = (int)x0, yi = (int)y0;
    const float* xp = x + (b * 128 + g * 32 + c) * HWHW;
    float v00 = 0.f, v10 = 0.f, v01 = 0.f, v11 = 0.f;
    bool okx0 = (xi >= 0) & (xi < 48), okx1 = (xi + 1 >= 0) & (xi + 1 < 48);
    if (yi >= 0 && yi < 48) {
      if (okx0) v00 = xp[yi * 48 + xi];
      if (okx1) v10 = xp[yi * 48 + xi + 1];
    }
    if (yi + 1 >= 0 && yi + 1 < 48) {
      if (okx0) v01 = xp[(yi + 1) * 48 + xi];
      if (okx1) v11 = xp[(yi + 1) * 48 + xi + 1];
    }
    kvs[c][j] = v00 * (1.f - wx) * (1.f - wy) + v10 * wx * (1.f - wy)
              + v01 * (1.f - wx) * wy + v11 * wx * wy;
  }
  __syncthreads();
  {
    int j = t >> 5, d = t & 31;
    float ak = 0.f, av = 0.f;
#pragma unroll
    for (int c = 0; c < 32; ++c) {
      float val = kvs[c][j];
      ak += wkl[d][c] * val;
      av += wvl[d][c] * val;
    }
    int jg = hd * 12 + j;
    ktb[bg * 4608 + jg * 32 + d] = f2bf(ak);
    vtb[bg * 5120 + d * 160 + jg] = f2bf(av);
  }
  if (hd == 0) {   // zero the v K-pad for this bg (j = 144..159)
    for (int u = t; u < 512; u += 384)
      vtb[bg * 5120 + (u >> 4) * 160 + 144 + (u & 15)] = 0;
  }
}

// Fused attention: block = (bg, 16 q-rows), 256 thr = 4 waves.
__global__ __launch_bounds__(256) void attn_fused_kernel(
    const ushort* __restrict__ qt, const ushort* __restrict__ ktb,
    const ushort* __restrict__ vtb,
    const float* __restrict__ vn0, const float* __restrict__ vn1,
    const float* __restrict__ w0, const float* __restrict__ b0,
    const float* __restrict__ w1, const float* __restrict__ b1,
    const float* __restrict__ w2, const float* __restrict__ b2,
    ushort* __restrict__ outh) {
  __shared__ __align__(16) char smem[21888];
  float* Ls = (float*)smem;                    // [16][LSP] fp32; P bf16 at dwords 64..143
  ushort* kbf = (ushort*)(smem + 9472);        // [144][32] bf16 (P1)
  ushort* vbfT = (ushort*)(smem + 9472);       // [32][160] bf16 (P4), overlaps kbf
  ushort* qbf = (ushort*)(smem + 19712);       // [16][32] bf16
  float* sv0 = (float*)(smem + 20736);         // [144]
  float* sv1 = (float*)(smem + 21312);         // [144]

  int bg = blockIdx.y, b = bg >> 2, g = bg & 3;
  int i0 = blockIdx.x * 16;
  int t = threadIdx.x;
  int w = t >> 6, lane = t & 63;
  int lam = lane & 15, quad = lane >> 4;

  // ---- stage (uint4 copies — data is already bf16) ----
  {
    const uint4* src = (const uint4*)(ktb + bg * 4608);
    uint4* dst = (uint4*)kbf;
    for (int u = t; u < 576; u += 256) dst[u] = src[u];
    if (t < 128) ((uint4*)qbf)[t & 127] =
        ((const uint4*)(qt + ((long)bg * HWHW + i0) * 32))[t & 127];
  }
  if (t < JD) { sv0[t] = vn0[bg * JD + t]; sv1[t] = vn1[bg * JD + t]; }

  // ---- per-lane resident weights ----
  float w00r[8], w01r[8], b0r[8];
#pragma unroll
  for (int j = 0; j < 8; ++j) {
    int k = quad * 8 + j;
    w00r[j] = w0[k]; w01r[j] = w0[32 + k]; b0r[j] = b0[k];
  }
  short8 w1f0, w1f1;   // W1^T A-frags (m=n-out, k=c-in), two 16-row tiles
#pragma unroll
  for (int j = 0; j < 8; ++j) {
    int k = quad * 8 + j;
    w1f0[j] = (short)f2bf(w1[k * 32 + lam]);
    w1f1[j] = (short)f2bf(w1[k * 32 + 16 + lam]);
  }
  f32x4 zA, zB;       // b1 folded into C-init (n = quad*4+r / 16+quad*4+r)
  float w2r[8];
#pragma unroll
  for (int r = 0; r < 4; ++r) {
    zA[r] = b1[quad * 4 + r];
    zB[r] = b1[16 + quad * 4 + r];
    w2r[r] = w2[quad * 4 + r];
    w2r[4 + r] = w2[16 + quad * 4 + r];
  }
  float b2s = b2[0];

  __syncthreads();   // B1

  // ---- P1: sim = q·kT (scaled); 9 N-tiles round-robin over 4 waves ----
  const float scale = 0.17677669529663687f;   // 32^-0.5
  {
    short8 aq = *(const short8*)(qbf + lam * 32 + quad * 8);
#pragma unroll 1
    for (int jt = w; jt < 9; jt += 4) {
      short8 bk = *(const short8*)(kbf + (jt * 16 + lam) * 32 + quad * 8);
      f32x4 acc = {0.f, 0.f, 0.f, 0.f};
      acc = __builtin_amdgcn_mfma_f32_16x16x32_bf16(aq, bk, acc, 0, 0, 0);
#pragma unroll
      for (int r = 0; r < 4; ++r)
        Ls[(quad * 4 + r) * LSP + jt * 16 + lam] = acc[r] * scale;
    }
  }
  __syncthreads();   // B2

  // ---- P2: CPB bias; wave owns 4 rows => 9 sub-iters of 64 pairs.
  // Transposed middle layer: D = W1^T·h1^T = h2^T, so lane holds its own
  // pair's h2 slice in C-regs; reduce = in-lane fma chain + 2 shfl_xor.
#pragma unroll 1
  for (int s = 0; s < 9; ++s) {
    int P = s * 64 + lane;
    int ii = P / 144, jj = P - ii * 144;
    int ig = i0 + w * 4 + ii;
    int iy = ig / 48, ix = ig - iy * 48;
    float p0 = (float)ix * (2.f / 47.f) - 1.f - sv0[jj];
    float p1 = (float)iy * (2.f / 47.f) - 1.f - sv1[jj];
    float s0f = copysignf(__logf(1.f + fabsf(p0)), p0);
    float s1f = copysignf(__logf(1.f + fabsf(p1)), p1);
    float bm[4];
#pragma unroll
    for (int mt = 0; mt < 4; ++mt) {
      float s0 = __shfl(s0f, mt * 16 + lam, 64);
      float s1 = __shfl(s1f, mt * 16 + lam, 64);
      float h[8];
#pragma unroll
      for (int j = 0; j < 8; ++j)
        h[j] = fmaxf(fmaf(s0, w00r[j], fmaf(s1, w01r[j], b0r[j])), 0.f);
      union { uint u[4]; short8 s8; } cvt;   // truncating f32->bf16 pack
#pragma unroll
      for (int j = 0; j < 4; ++j)
        cvt.u[j] = __builtin_amdgcn_perm(__float_as_uint(h[2 * j + 1]),
                                         __float_as_uint(h[2 * j]), 0x07060302);
      f32x4 dA = __builtin_amdgcn_mfma_f32_16x16x32_bf16(w1f0, cvt.s8, zA, 0, 0, 0);
      f32x4 dB = __builtin_amdgcn_mfma_f32_16x16x32_bf16(w1f1, cvt.s8, zB, 0, 0, 0);
      float acc = 0.f;
#pragma unroll
      for (int r = 0; r < 4; ++r) {
        acc = fmaf(fmaxf(dA[r], 0.f), w2r[r], acc);
        acc = fmaf(fmaxf(dB[r], 0.f), w2r[4 + r], acc);
      }
      acc += __shfl_xor(acc, 16, 64);
      acc += __shfl_xor(acc, 32, 64);
      bm[mt] = acc;
    }
    float biasv = (quad == 0 ? bm[0] : quad == 1 ? bm[1] : quad == 2 ? bm[2] : bm[3]) + b2s;
    Ls[(w * 4 + ii) * LSP + jj] += biasv;
  }
  __syncthreads();   // B3

  // ---- stage vT bf16 (overlaps kbf, dead after P1); pad pre-zeroed in global ----
  {
    const uint4* src = (const uint4*)(vtb + bg * 5120);
    uint4* dst = (uint4*)vbfT;
    for (int u = t; u < 640; u += 256) dst[u] = src[u];
  }

  // ---- P3: softmax per row (wave owns 4 rows); P packed bf16 in-place ----
#pragma unroll 1
  for (int rr = 0; rr < 4; ++rr) {
    int row = w * 4 + rr;
    const float* Lp = Ls + row * LSP;
    float l0 = Lp[lane], l1 = Lp[64 + lane];
    float l2 = (lane < 16) ? Lp[128 + lane] : -INFINITY;
    float m = fmaxf(fmaxf(l0, l1), l2);
#pragma unroll
    for (int k = 32; k >= 1; k >>= 1) m = fmaxf(m, __shfl_xor(m, k, 64));
    float e0 = __expf(l0 - m), e1 = __expf(l1 - m);
    float e2 = (lane < 16) ? __expf(l2 - m) : 0.f;
    float sum = e0 + e1 + e2;
#pragma unroll
    for (int k = 32; k >= 1; k >>= 1) sum += __shfl_xor(sum, k, 64);
    float inv = 1.f / sum;
    ushort* pb = (ushort*)(Lp + 64);
    pb[lane] = f2bf(e0 * inv);
    pb[64 + lane] = f2bf(e1 * inv);
    if (lane < 32) pb[128 + lane] = (lane < 16) ? f2bf(e2 * inv) : (ushort)0;
  }
  __syncthreads();   // B4

  // ---- P4: O = P·v (K=160, zero-padded); waves 0,1 take the 2 col-halves ----
  if (w < 2) {
    f32x4 o = {0.f, 0.f, 0.f, 0.f};
    const ushort* pb = (const ushort*)(Ls + lam * LSP + 64);
    const ushort* vb = vbfT + (w * 16 + lam) * 160;
#pragma unroll
    for (int kb = 0; kb < 5; ++kb) {
      short8 ap = *(const short8*)(pb + kb * 32 + quad * 8);
      short8 bv = *(const short8*)(vb + kb * 32 + quad * 8);
      o = __builtin_amdgcn_mfma_f32_16x16x32_bf16(ap, bv, o, 0, 0, 0);
    }
#pragma unroll
    for (int r = 0; r < 4; ++r) {
      int ig = i0 + quad * 4 + r;
      outh[((long)b * HWHW + ig) * 128 + g * 32 + w * 16 + lam] = f2bf(o[r]);
    }
  }
}

// grid (144 hw-chunks, 2 b), 256 thr = 4 waves. MFMA out-proj:
// out[hw][oc] = outh[hw][c] · wo[oc][c]^T; wave w owns oc in [w*32, w*32+32).
__global__ __launch_bounds__(256) void out_kernel(
    const ushort* __restrict__ outh, const float* __restrict__ wo,
    const float* __restrict__ bo, const float* __restrict__ x,
    const float* __restrict__ gamma, float* __restrict__ out) {
  __shared__ __align__(16) char smem[39168];
  ushort* wob = (ushort*)smem;                 // [128][136] bf16 (pad +8: b128 reads ~2-way)
  ushort* aob = (ushort*)(smem + 34816);       // [16][136] bf16
  int b = blockIdx.y;
  int hw0 = blockIdx.x * 16;
  int t = threadIdx.x;
  int w = t >> 6, lane = t & 63, lam = lane & 15, quad = lane >> 4;
  // stage wo -> bf16 (float2 loads, packed dword LDS writes)
  {
    const float2* wsrc = (const float2*)wo;
    for (int u = t; u < 8192; u += 256) {
      float2 v = wsrc[u];
      ((uint*)wob)[(u >> 6) * 68 + (u & 63)] =
          (uint)f2bf(v.x) | ((uint)f2bf(v.y) << 16);
    }
  }
  // stage outh tile (already bf16): 1024 dwords
  {
    const uint* src = (const uint*)(outh + ((long)b * HWHW + hw0) * 128);
    for (int u = t; u < 1024; u += 256)
      ((uint*)aob)[(u >> 6) * 68 + (u & 63)] = src[u];
  }
  __syncthreads();
  f32x4 acc0 = {0.f, 0.f, 0.f, 0.f}, acc1 = {0.f, 0.f, 0.f, 0.f};
#pragma unroll
  for (int ks = 0; ks < 4; ++ks) {
    short8 a = *(const short8*)(aob + lam * 136 + ks * 32 + quad * 8);
    short8 b0f = *(const short8*)(wob + (w * 32 + lam) * 136 + ks * 32 + quad * 8);
    short8 b1f = *(const short8*)(wob + (w * 32 + 16 + lam) * 136 + ks * 32 + quad * 8);
    acc0 = __builtin_amdgcn_mfma_f32_16x16x32_bf16(a, b0f, acc0, 0, 0, 0);
    acc1 = __builtin_amdgcn_mfma_f32_16x16x32_bf16(a, b1f, acc1, 0, 0, 0);
  }
  float gm = gamma[0];
  float* out0 = out;
  float* out1 = out + 2 * 128 * HWHW;
#pragma unroll
  for (int nt = 0; nt < 2; ++nt) {
    f32x4 acc = nt ? acc1 : acc0;
    int oc = w * 32 + nt * 16 + lam;
    float bv = bo[oc];
    long base = ((long)(b * 128 + oc)) * HWHW + hw0 + quad * 4;
    float4 xv = *(const float4*)(x + base);
    float4 a1, a0;
    a1.x = acc[0] + bv; a1.y = acc[1] + bv; a1.z = acc[2] + bv; a1.w = acc[3] + bv;
    a0.x = fmaf(gm, a1.x, xv.x); a0.y = fmaf(gm, a1.y, xv.y);
    a0.z = fmaf(gm, a1.z, xv.z); a0.w = fmaf(gm, a1.w, xv.w);
    *(float4*)(out1 + base) = a1;
    *(float4*)(out0 + base) = a0;
  }
}

extern "C" void kernel_launch(void* const* d_in, const int* in_sizes, int n_in,
                              void* d_out, int out_size, void* d_ws, size_t ws_size,
                              hipStream_t stream) {
  const float* x     = (const float*)d_in[0];
  const float* gamma = (const float*)d_in[1];
  const float* wq    = (const float*)d_in[2];
  const float* wk    = (const float*)d_in[3];
  const float* wv    = (const float*)d_in[4];
  const float* wo    = (const float*)d_in[5];
  const float* bo    = (const float*)d_in[6];
  const float* wdw   = (const float*)d_in[7];
  const float* bdw   = (const float*)d_in[8];
  const float* wproj = (const float*)d_in[9];
  const float* cw0   = (const float*)d_in[10];
  const float* cb0   = (const float*)d_in[11];
  const float* cw1   = (const float*)d_in[12];
  const float* cb1   = (const float*)d_in[13];
  const float* cw2   = (const float*)d_in[14];
  const float* cb2   = (const float*)d_in[15];
  char* wsb = (char*)d_ws;
  ushort* qt  = (ushort*)wsb;
  float* vn0  = (float*)(wsb + 1179648);
  float* vn1  = (float*)(wsb + 1184256);
  ushort* ktb = (ushort*)(wsb + 1188864);
  ushort* vtb = (ushort*)(wsb + 1262592);
  ushort* outh = (ushort*)(wsb + 1344512);
  float* out  = (float*)d_out;

  qproj_kernel<<<dim3(9, 4, 8), 256, 0, stream>>>(x, wq, qt);
  offset_kv_kernel<<<dim3(12, 8), 384, 0, stream>>>(qt, wdw, bdw, wproj, x, wk, wv,
                                                    vn0, vn1, ktb, vtb);
  attn_fused_kernel<<<dim3(144, 8), 256, 0, stream>>>(qt, ktb, vtb, vn0, vn1,
                                                      cw0, cb0, cw1, cb1, cw2, cb2, outh);
  out_kernel<<<dim3(144, 2), 256, 0, stream>>>(outh, wo, bo, x, gamma, out);
}

// Round 7
// 135.622 us; speedup vs baseline: 4.2190x; 1.0176x over previous
//
#include <hip/hip_runtime.h>
#include <math.h>

// dims
#define HWHW 2304   // 48*48
#define JD   144    // 12*12
#define LSP  148    // Ls row stride in dwords

typedef __attribute__((ext_vector_type(8))) short short8;
typedef __attribute__((ext_vector_type(4))) float f32x4;

__device__ inline ushort f2bf(float f) {
  uint u = __float_as_uint(f);
  u += 0x7fffu + ((u >> 16) & 1u);   // RNE
  return (ushort)(u >> 16);
}
__device__ inline float bf2f(ushort s) { return __uint_as_float((uint)s << 16); }
__device__ inline uint packbf(float hi, float lo) {   // truncating {hi16(hi),hi16(lo)}
  return __builtin_amdgcn_perm(__float_as_uint(hi), __float_as_uint(lo), 0x07060302);
}

// ws layout (byte offsets)
// qt_bf   [8][2304][32] u16  @ 0         (1179648 B)
// vn0     [8][144] f32       @ 1179648
// vn1     [8][144] f32       @ 1184256
// kt_bf   [8][144][32] u16   @ 1188864   (73728 B)
// vtT_bf  [8][32][160] u16   @ 1262592   (81920 B, j=144..159 zeroed)
// outh_bf [2][2304][128] u16 @ 1344512   (1179648 B, end 2524160 B)

// grid (9 hw-chunks, 4 o-chunks, 8 bg): thread holds 32 x-ch in regs, computes 8 o -> bf16 qt.
__global__ __launch_bounds__(256) void qproj_kernel(
    const float* __restrict__ x, const float* __restrict__ wq,
    ushort* __restrict__ qt) {
  int hw = blockIdx.x * 256 + threadIdx.x;
  int o0 = blockIdx.y * 8, bg = blockIdx.z;
  int b = bg >> 2, g = bg & 3;
  const float* xp = x + (b * 128 + g * 32) * HWHW + hw;
  float xv[32];
#pragma unroll
  for (int c = 0; c < 32; ++c) xv[c] = xp[c * HWHW];
  uint p[4];
#pragma unroll
  for (int oo = 0; oo < 8; oo += 2) {
    const float* w0r = wq + (g * 32 + o0 + oo) * 32;       // uniform -> scalar
    const float* w1r = wq + (g * 32 + o0 + oo + 1) * 32;
    float a0 = 0.f, a1 = 0.f;
#pragma unroll
    for (int c = 0; c < 32; ++c) { a0 += w0r[c] * xv[c]; a1 += w1r[c] * xv[c]; }
    p[oo >> 1] = (uint)f2bf(a0) | ((uint)f2bf(a1) << 16);
  }
  *(uint4*)(qt + ((long)bg * HWHW + hw) * 32 + o0) = make_uint4(p[0], p[1], p[2], p[3]);
}

// grid (12 hd, 8 bg), 384 thr. Fused: depthwise conv -> GELU -> proj -> tanh ->
// grid coords -> bilinear sample -> k/v proj (bf16 out).
__global__ __launch_bounds__(384) void offset_kv_kernel(
    const ushort* __restrict__ qt, const float* __restrict__ wdw,
    const float* __restrict__ bdw, const float* __restrict__ wproj,
    const float* __restrict__ x, const float* __restrict__ wk,
    const float* __restrict__ wv,
    float* __restrict__ vn0, float* __restrict__ vn1,
    ushort* __restrict__ ktb, ushort* __restrict__ vtb) {
  __shared__ float qs[288][32];      // [ry*48+col][c] — conflict-free both ways
  __shared__ float wdws[36][32];     // [k][c]
  __shared__ float wkl[32][33], wvl[32][33];   // [d][c]
  __shared__ float kvs[32][13];      // [c][j] (+pad)
  __shared__ float spx[12], spy[12];
  int hd = blockIdx.x, bg = blockIdx.y, b = bg >> 2, g = bg & 3;
  int t = threadIdx.x;
  for (int u = t; u < 4608; u += 384) {   // uint loads: 2 channels per lane
    int r = u >> 4, c2 = u & 15;
    int ry = r / 48, col = r - ry * 48;
    int hy = hd * 4 - 1 + ry;
    uint v = 0;
    if (hy >= 0 && hy < 48)
      v = ((const uint*)qt)[((long)bg * HWHW + hy * 48 + col) * 16 + c2];
    qs[r][c2 * 2] = bf2f((ushort)v);
    qs[r][c2 * 2 + 1] = bf2f((ushort)(v >> 16));
  }
  for (int u = t; u < 1152; u += 384) wdws[u >> 5][u & 31] = wdw[(u & 31) * 36 + (u >> 5)];
  for (int u = t; u < 1024; u += 384) {
    int d = u >> 5, c = u & 31;
    wkl[d][c] = wk[g * 1024 + u];
    wvl[d][c] = wv[g * 1024 + u];
  }
  __syncthreads();
  {
    int wd = t >> 5, c = t & 31;
    float s = 0.f;
#pragma unroll
    for (int ky = 0; ky < 6; ++ky) {
#pragma unroll
      for (int kx = 0; kx < 6; ++kx) {
        int wx = wd * 4 - 1 + kx;
        if (wx >= 0 && wx < 48)
          s += wdws[ky * 6 + kx][c] * qs[ky * 48 + wx][c];
      }
    }
    s += bdw[c];
    s = 0.5f * s * (1.f + erff(s * 0.70710678118654752f));  // exact GELU
    float g0 = wproj[c] * s;
    float g1 = wproj[32 + c] * s;
#pragma unroll
    for (int k = 16; k >= 1; k >>= 1) {
      g0 += __shfl_xor(g0, k, 64);
      g1 += __shfl_xor(g1, k, 64);
    }
    if (c == 0) {
      float off0 = tanhf(g0) * 4.f;
      float off1 = tanhf(g1) * 4.f;
      float n0 = 2.f * ((float)wd + off0) / 11.f - 1.f;
      float n1 = 2.f * ((float)hd + off1) / 11.f - 1.f;
      int idx = bg * JD + hd * 12 + wd;
      vn0[idx] = n0;
      vn1[idx] = n1;
      spx[wd] = ((n0 + 1.f) * 48.f - 1.f) * 0.5f;
      spy[wd] = ((n1 + 1.f) * 48.f - 1.f) * 0.5f;
    }
  }
  __syncthreads();
  {
    int j = t >> 5, c = t & 31;
    float fx = spx[j], fy = spy[j];
    float x0 = floorf(fx), y0 = floorf(fy);
    float wx = fx - x0, wy = fy - y0;
    int xi = (int)x0, yi = (int)y0;
    const float* xp = x + (b * 128 + g * 32 + c) * HWHW;
    float v00 = 0.f, v10 = 0.f, v01 = 0.f, v11 = 0.f;
    bool okx0 = (xi >= 0) & (xi < 48), okx1 = (xi + 1 >= 0) & (xi + 1 < 48);
    if (yi >= 0 && yi < 48) {
      if (okx0) v00 = xp[yi * 48 + xi];
      if (okx1) v10 = xp[yi * 48 + xi + 1];
    }
    if (yi + 1 >= 0 && yi + 1 < 48) {
      if (okx0) v01 = xp[(yi + 1) * 48 + xi];
      if (okx1) v11 = xp[(yi + 1) * 48 + xi + 1];
    }
    kvs[c][j] = v00 * (1.f - wx) * (1.f - wy) + v10 * wx * (1.f - wy)
              + v01 * (1.f - wx) * wy + v11 * wx * wy;
  }
  __syncthreads();
  {
    int j = t >> 5, d = t & 31;
    float ak = 0.f, av = 0.f;
#pragma unroll
    for (int c = 0; c < 32; ++c) {
      float val = kvs[c][j];
      ak += wkl[d][c] * val;
      av += wvl[d][c] * val;
    }
    int jg = hd * 12 + j;
    ktb[bg * 4608 + jg * 32 + d] = f2bf(ak);
    vtb[bg * 5120 + d * 160 + jg] = f2bf(av);
  }
  if (hd == 0) {   // zero the v K-pad for this bg (j = 144..159)
    for (int u = t; u < 512; u += 384)
      vtb[bg * 5120 + (u >> 4) * 160 + 144 + (u & 15)] = 0;
  }
}

// Fused attention: block = (bg, 16 q-rows), 256 thr = 4 waves.
// MFMA operands (q/k/v) load DIRECTLY from global (tiles are contiguous in
// fragment order; L2 serves the 144-block re-reads). LDS holds only Ls + sv.
__global__ __launch_bounds__(256) void attn_fused_kernel(
    const ushort* __restrict__ qt, const ushort* __restrict__ ktb,
    const ushort* __restrict__ vtb,
    const float* __restrict__ vn0, const float* __restrict__ vn1,
    const float* __restrict__ w0, const float* __restrict__ b0,
    const float* __restrict__ w1, const float* __restrict__ b1,
    const float* __restrict__ w2, const float* __restrict__ b2,
    ushort* __restrict__ outh) {
  __shared__ __align__(16) char smem[10624];
  float* Ls = (float*)smem;                    // [16][LSP] fp32; P bf16 at dwords 64..143
  float* sv0 = (float*)(smem + 9472);          // [144]
  float* sv1 = (float*)(smem + 10048);         // [144]

  int bg = blockIdx.y, b = bg >> 2, g = bg & 3;
  int i0 = blockIdx.x * 16;
  int t = threadIdx.x;
  int w = t >> 6, lane = t & 63;
  int lam = lane & 15, quad = lane >> 4;

  if (t < JD) { sv0[t] = vn0[bg * JD + t]; sv1[t] = vn1[bg * JD + t]; }

  // ---- per-lane resident weights ----
  float w00r[8], w01r[8], b0r[8];
#pragma unroll
  for (int j = 0; j < 8; ++j) {
    int k = quad * 8 + j;
    w00r[j] = w0[k]; w01r[j] = w0[32 + k]; b0r[j] = b0[k];
  }
  short8 w1f0, w1f1;   // W1^T A-frags (m=n-out, k=c-in), two 16-row tiles
#pragma unroll
  for (int j = 0; j < 8; ++j) {
    int k = quad * 8 + j;
    w1f0[j] = (short)f2bf(w1[k * 32 + lam]);
    w1f1[j] = (short)f2bf(w1[k * 32 + 16 + lam]);
  }
  f32x4 zA, zB;       // b1 folded into C-init (n = quad*4+r / 16+quad*4+r)
  float w2r[8];
#pragma unroll
  for (int r = 0; r < 4; ++r) {
    zA[r] = b1[quad * 4 + r];
    zB[r] = b1[16 + quad * 4 + r];
    w2r[r] = w2[quad * 4 + r];
    w2r[4 + r] = w2[16 + quad * 4 + r];
  }
  float b2s = b2[0];

  // ---- P1: sim = q·kT (scaled); operands straight from global ----
  const float scale = 0.17677669529663687f;   // 32^-0.5
  {
    short8 aq = *(const short8*)(qt + ((long)bg * HWHW + i0 + lam) * 32 + quad * 8);
    const ushort* kb = ktb + bg * 4608;
#pragma unroll 1
    for (int jt = w; jt < 9; jt += 4) {
      short8 bk = *(const short8*)(kb + (jt * 16 + lam) * 32 + quad * 8);
      f32x4 acc = {0.f, 0.f, 0.f, 0.f};
      acc = __builtin_amdgcn_mfma_f32_16x16x32_bf16(aq, bk, acc, 0, 0, 0);
#pragma unroll
      for (int r = 0; r < 4; ++r)
        Ls[(quad * 4 + r) * LSP + jt * 16 + lam] = acc[r] * scale;
    }
  }
  __syncthreads();   // B2

  // ---- P2: CPB bias; wave owns 4 rows => 9 sub-iters of 64 pairs.
  // Transposed middle layer: D = W1^T·h1^T = h2^T, so lane holds its own
  // pair's h2 slice in C-regs; reduce = in-lane fma chain + 2 shfl_xor.
#pragma unroll 1
  for (int s = 0; s < 9; ++s) {
    int P = s * 64 + lane;
    int ii = P / 144, jj = P - ii * 144;
    int ig = i0 + w * 4 + ii;
    int iy = ig / 48, ix = ig - iy * 48;
    float p0 = (float)ix * (2.f / 47.f) - 1.f - sv0[jj];
    float p1 = (float)iy * (2.f / 47.f) - 1.f - sv1[jj];
    float s0f = copysignf(__logf(1.f + fabsf(p0)), p0);
    float s1f = copysignf(__logf(1.f + fabsf(p1)), p1);
    float bm[4];
#pragma unroll
    for (int mt = 0; mt < 4; ++mt) {
      float s0 = __shfl(s0f, mt * 16 + lam, 64);
      float s1 = __shfl(s1f, mt * 16 + lam, 64);
      float h[8];
#pragma unroll
      for (int j = 0; j < 8; ++j)
        h[j] = fmaxf(fmaf(s0, w00r[j], fmaf(s1, w01r[j], b0r[j])), 0.f);
      union { uint u[4]; short8 s8; } cvt;   // truncating f32->bf16 pack
#pragma unroll
      for (int j = 0; j < 4; ++j) cvt.u[j] = packbf(h[2 * j + 1], h[2 * j]);
      f32x4 dA = __builtin_amdgcn_mfma_f32_16x16x32_bf16(w1f0, cvt.s8, zA, 0, 0, 0);
      f32x4 dB = __builtin_amdgcn_mfma_f32_16x16x32_bf16(w1f1, cvt.s8, zB, 0, 0, 0);
      float acc = 0.f;
#pragma unroll
      for (int r = 0; r < 4; ++r) {
        acc = fmaf(fmaxf(dA[r], 0.f), w2r[r], acc);
        acc = fmaf(fmaxf(dB[r], 0.f), w2r[4 + r], acc);
      }
      acc += __shfl_xor(acc, 16, 64);
      acc += __shfl_xor(acc, 32, 64);
      bm[mt] = acc;
    }
    float biasv = (quad == 0 ? bm[0] : quad == 1 ? bm[1] : quad == 2 ? bm[2] : bm[3]) + b2s;
    Ls[(w * 4 + ii) * LSP + jj] += biasv;
  }
  __syncthreads();   // B3

  // ---- P3: softmax per row (wave owns 4 rows); P packed bf16 in-place ----
#pragma unroll 1
  for (int rr = 0; rr < 4; ++rr) {
    int row = w * 4 + rr;
    const float* Lp = Ls + row * LSP;
    float l0 = Lp[lane], l1 = Lp[64 + lane];
    float l2 = (lane < 16) ? Lp[128 + lane] : -INFINITY;
    float m = fmaxf(fmaxf(l0, l1), l2);
#pragma unroll
    for (int k = 32; k >= 1; k >>= 1) m = fmaxf(m, __shfl_xor(m, k, 64));
    float e0 = __expf(l0 - m), e1 = __expf(l1 - m);
    float e2 = (lane < 16) ? __expf(l2 - m) : 0.f;
    float sum = e0 + e1 + e2;
#pragma unroll
    for (int k = 32; k >= 1; k >>= 1) sum += __shfl_xor(sum, k, 64);
    float inv = 1.f / sum;
    ushort* pb = (ushort*)(Lp + 64);
    pb[lane] = f2bf(e0 * inv);
    pb[64 + lane] = f2bf(e1 * inv);
    if (lane < 32) pb[128 + lane] = (lane < 16) ? f2bf(e2 * inv) : (ushort)0;
  }
  __syncthreads();   // B4

  // ---- P4: O = P·v (K=160, zero-padded); waves 0,1 take the 2 col-halves ----
  if (w < 2) {
    f32x4 o = {0.f, 0.f, 0.f, 0.f};
    const ushort* pb = (const ushort*)(Ls + lam * LSP + 64);
    const ushort* vb = vtb + bg * 5120 + (w * 16 + lam) * 160;   // global direct
#pragma unroll
    for (int kb = 0; kb < 5; ++kb) {
      short8 ap = *(const short8*)(pb + kb * 32 + quad * 8);
      short8 bv = *(const short8*)(vb + kb * 32 + quad * 8);
      o = __builtin_amdgcn_mfma_f32_16x16x32_bf16(ap, bv, o, 0, 0, 0);
    }
#pragma unroll
    for (int r = 0; r < 4; ++r) {
      int ig = i0 + quad * 4 + r;
      outh[((long)b * HWHW + ig) * 128 + g * 32 + w * 16 + lam] = f2bf(o[r]);
    }
  }
}

// grid (144 hw-chunks, 2 b), 256 thr = 4 waves. MFMA out-proj, zero LDS:
// A-frags straight from bf16 outh; B-frags from fp32 wo with inline v_perm pack.
__global__ __launch_bounds__(256) void out_kernel(
    const ushort* __restrict__ outh, const float* __restrict__ wo,
    const float* __restrict__ bo, const float* __restrict__ x,
    const float* __restrict__ gamma, float* __restrict__ out) {
  int b = blockIdx.y;
  int hw0 = blockIdx.x * 16;
  int t = threadIdx.x;
  int w = t >> 6, lane = t & 63, lam = lane & 15, quad = lane >> 4;
  const ushort* abase = outh + ((long)b * HWHW + hw0 + lam) * 128 + quad * 8;
  const float* wb0 = wo + (w * 32 + lam) * 128 + quad * 8;
  const float* wb1 = wo + (w * 32 + 16 + lam) * 128 + quad * 8;
  f32x4 acc0 = {0.f, 0.f, 0.f, 0.f}, acc1 = {0.f, 0.f, 0.f, 0.f};
#pragma unroll
  for (int ks = 0; ks < 4; ++ks) {
    short8 a = *(const short8*)(abase + ks * 32);
    float4 wa = *(const float4*)(wb0 + ks * 32);
    float4 wb = *(const float4*)(wb0 + ks * 32 + 4);
    float4 wc = *(const float4*)(wb1 + ks * 32);
    float4 wd = *(const float4*)(wb1 + ks * 32 + 4);
    union { uint u[4]; short8 s8; } p0, p1;
    p0.u[0] = packbf(wa.y, wa.x); p0.u[1] = packbf(wa.w, wa.z);
    p0.u[2] = packbf(wb.y, wb.x); p0.u[3] = packbf(wb.w, wb.z);
    p1.u[0] = packbf(wc.y, wc.x); p1.u[1] = packbf(wc.w, wc.z);
    p1.u[2] = packbf(wd.y, wd.x); p1.u[3] = packbf(wd.w, wd.z);
    acc0 = __builtin_amdgcn_mfma_f32_16x16x32_bf16(a, p0.s8, acc0, 0, 0, 0);
    acc1 = __builtin_amdgcn_mfma_f32_16x16x32_bf16(a, p1.s8, acc1, 0, 0, 0);
  }
  float gm = gamma[0];
  float* out0 = out;
  float* out1 = out + 2 * 128 * HWHW;
#pragma unroll
  for (int nt = 0; nt < 2; ++nt) {
    f32x4 acc = nt ? acc1 : acc0;
    int oc = w * 32 + nt * 16 + lam;
    float bv = bo[oc];
    long base = ((long)(b * 128 + oc)) * HWHW + hw0 + quad * 4;
    float4 xv = *(const float4*)(x + base);
    float4 a1, a0;
    a1.x = acc[0] + bv; a1.y = acc[1] + bv; a1.z = acc[2] + bv; a1.w = acc[3] + bv;
    a0.x = fmaf(gm, a1.x, xv.x); a0.y = fmaf(gm, a1.y, xv.y);
    a0.z = fmaf(gm, a1.z, xv.z); a0.w = fmaf(gm, a1.w, xv.w);
    *(float4*)(out1 + base) = a1;
    *(float4*)(out0 + base) = a0;
  }
}

extern "C" void kernel_launch(void* const* d_in, const int* in_sizes, int n_in,
                              void* d_out, int out_size, void* d_ws, size_t ws_size,
                              hipStream_t stream) {
  const float* x     = (const float*)d_in[0];
  const float* gamma = (const float*)d_in[1];
  const float* wq    = (const float*)d_in[2];
  const float* wk    = (const float*)d_in[3];
  const float* wv    = (const float*)d_in[4];
  const float* wo    = (const float*)d_in[5];
  const float* bo    = (const float*)d_in[6];
  const float* wdw   = (const float*)d_in[7];
  const float* bdw   = (const float*)d_in[8];
  const float* wproj = (const float*)d_in[9];
  const float* cw0   = (const float*)d_in[10];
  const float* cb0   = (const float*)d_in[11];
  const float* cw1   = (const float*)d_in[12];
  const float* cb1   = (const float*)d_in[13];
  const float* cw2   = (const float*)d_in[14];
  const float* cb2   = (const float*)d_in[15];
  char* wsb = (char*)d_ws;
  ushort* qt  = (ushort*)wsb;
  float* vn0  = (float*)(wsb + 1179648);
  float* vn1  = (float*)(wsb + 1184256);
  ushort* ktb = (ushort*)(wsb + 1188864);
  ushort* vtb = (ushort*)(wsb + 1262592);
  ushort* outh = (ushort*)(wsb + 1344512);
  float* out  = (float*)d_out;

  qproj_kernel<<<dim3(9, 4, 8), 256, 0, stream>>>(x, wq, qt);
  offset_kv_kernel<<<dim3(12, 8), 384, 0, stream>>>(qt, wdw, bdw, wproj, x, wk, wv,
                                                    vn0, vn1, ktb, vtb);
  attn_fused_kernel<<<dim3(144, 8), 256, 0, stream>>>(qt, ktb, vtb, vn0, vn1,
                                                      cw0, cb0, cw1, cb1, cw2, cb2, outh);
  out_kernel<<<dim3(144, 2), 256, 0, stream>>>(outh, wo, bo, x, gamma, out);
}

// Round 8
// 132.019 us; speedup vs baseline: 4.3341x; 1.0273x over previous
//
#include <hip/hip_runtime.h>
#include <math.h>

// dims
#define HWHW 2304   // 48*48
#define JD   144    // 12*12
#define LSP  148    // Ls row stride in dwords

typedef __attribute__((ext_vector_type(8))) short short8;
typedef __attribute__((ext_vector_type(4))) float f32x4;

__device__ inline ushort f2bf(float f) {
  uint u = __float_as_uint(f);
  u += 0x7fffu + ((u >> 16) & 1u);   // RNE
  return (ushort)(u >> 16);
}
__device__ inline float bf2f(ushort s) { return __uint_as_float((uint)s << 16); }
__device__ inline uint packbf(float hi, float lo) {   // truncating {hi16(hi),hi16(lo)}
  return __builtin_amdgcn_perm(__float_as_uint(hi), __float_as_uint(lo), 0x07060302);
}

// ws layout (byte offsets)
// vn0     [8][144] f32       @ 0
// vn1     [8][144] f32       @ 4608
// kt_bf   [8][144][32] u16   @ 9216    (73728 B)
// vtT_bf  [8][32][160] u16   @ 82944   (81920 B, j=144..159 zeroed)
// outh_bf [2][2304][128] u16 @ 164864  (1179648 B, end 1344512 B)

// grid (12 hd, 8 bg), 384 thr = 6 waves. Fused: q=Wq·x via MFMA (wave w owns
// conv input row ry=w) -> depthwise conv -> GELU -> proj -> tanh -> grid coords
// -> bilinear sample -> k/v proj (bf16 out).
__global__ __launch_bounds__(384) void offset_kv_kernel(
    const float* __restrict__ x, const float* __restrict__ wq,
    const float* __restrict__ wdw, const float* __restrict__ bdw,
    const float* __restrict__ wproj, const float* __restrict__ wk,
    const float* __restrict__ wv,
    float* __restrict__ vn0, float* __restrict__ vn1,
    ushort* __restrict__ ktb, ushort* __restrict__ vtb) {
  __shared__ float qs[288][33];      // [ry*48+col][c], +1 pad
  __shared__ float wdws[36][32];     // [k][c]
  __shared__ float wkl[32][33], wvl[32][33];   // [d][c]
  __shared__ float kvs[32][13];      // [c][j] (+pad)
  __shared__ float spx[12], spy[12];
  int hd = blockIdx.x, bg = blockIdx.y, b = bg >> 2, g = bg & 3;
  int t = threadIdx.x;
  int w = t >> 6, lane = t & 63, lam = lane & 15, quad = lane >> 4;

  // ---- q-tile via MFMA: wave w computes conv-input row ry=w (hy=hd*4-1+w) ----
  {
    int hy = hd * 4 - 1 + w;
    if (hy >= 0 && hy < 48) {
      // B-frags of Wq^T (shared by the wave's 3 tiles)
      const float* wqg = wq + (g * 32) * 32;
      float4 wa = *(const float4*)(wqg + lam * 32 + quad * 8);
      float4 wb = *(const float4*)(wqg + lam * 32 + quad * 8 + 4);
      float4 wc = *(const float4*)(wqg + (16 + lam) * 32 + quad * 8);
      float4 wd = *(const float4*)(wqg + (16 + lam) * 32 + quad * 8 + 4);
      union { uint u[4]; short8 s8; } bf0, bf1;
      bf0.u[0] = packbf(wa.y, wa.x); bf0.u[1] = packbf(wa.w, wa.z);
      bf0.u[2] = packbf(wb.y, wb.x); bf0.u[3] = packbf(wb.w, wb.z);
      bf1.u[0] = packbf(wc.y, wc.x); bf1.u[1] = packbf(wc.w, wc.z);
      bf1.u[2] = packbf(wd.y, wd.x); bf1.u[3] = packbf(wd.w, wd.z);
      const float* xg = x + (b * 128 + g * 32) * HWHW + hy * 48;
#pragma unroll
      for (int tt = 0; tt < 3; ++tt) {
        int col = tt * 16 + lam;
        union { uint u[4]; short8 s8; } xa;
#pragma unroll
        for (int j = 0; j < 4; ++j) {
          float x0 = xg[(quad * 8 + 2 * j) * HWHW + col];
          float x1 = xg[(quad * 8 + 2 * j + 1) * HWHW + col];
          xa.u[j] = packbf(x1, x0);
        }
        f32x4 z = {0.f, 0.f, 0.f, 0.f};
        f32x4 d0 = __builtin_amdgcn_mfma_f32_16x16x32_bf16(xa.s8, bf0.s8, z, 0, 0, 0);
        f32x4 d1 = __builtin_amdgcn_mfma_f32_16x16x32_bf16(xa.s8, bf1.s8, z, 0, 0, 0);
        int p = w * 48 + tt * 16 + quad * 4;
#pragma unroll
        for (int r = 0; r < 4; ++r) {
          qs[p + r][lam] = d0[r];
          qs[p + r][16 + lam] = d1[r];
        }
      }
    } else {
#pragma unroll
      for (int tt = 0; tt < 3; ++tt) {
        int p = w * 48 + tt * 16 + quad * 4;
#pragma unroll
        for (int r = 0; r < 4; ++r) {
          qs[p + r][lam] = 0.f;
          qs[p + r][16 + lam] = 0.f;
        }
      }
    }
  }
  for (int u = t; u < 1152; u += 384) wdws[u >> 5][u & 31] = wdw[(u & 31) * 36 + (u >> 5)];
  for (int u = t; u < 1024; u += 384) {
    int d = u >> 5, c = u & 31;
    wkl[d][c] = wk[g * 1024 + u];
    wvl[d][c] = wv[g * 1024 + u];
  }
  __syncthreads();
  {
    int wd = t >> 5, c = t & 31;
    float s = 0.f;
#pragma unroll
    for (int ky = 0; ky < 6; ++ky) {
#pragma unroll
      for (int kx = 0; kx < 6; ++kx) {
        int wx = wd * 4 - 1 + kx;
        if (wx >= 0 && wx < 48)
          s += wdws[ky * 6 + kx][c] * qs[ky * 48 + wx][c];
      }
    }
    s += bdw[c];
    s = 0.5f * s * (1.f + erff(s * 0.70710678118654752f));  // exact GELU
    float g0 = wproj[c] * s;
    float g1 = wproj[32 + c] * s;
#pragma unroll
    for (int k = 16; k >= 1; k >>= 1) {
      g0 += __shfl_xor(g0, k, 64);
      g1 += __shfl_xor(g1, k, 64);
    }
    if (c == 0) {
      float off0 = tanhf(g0) * 4.f;
      float off1 = tanhf(g1) * 4.f;
      float n0 = 2.f * ((float)wd + off0) / 11.f - 1.f;
      float n1 = 2.f * ((float)hd + off1) / 11.f - 1.f;
      int idx = bg * JD + hd * 12 + wd;
      vn0[idx] = n0;
      vn1[idx] = n1;
      spx[wd] = ((n0 + 1.f) * 48.f - 1.f) * 0.5f;
      spy[wd] = ((n1 + 1.f) * 48.f - 1.f) * 0.5f;
    }
  }
  __syncthreads();
  {
    int j = t >> 5, c = t & 31;
    float fx = spx[j], fy = spy[j];
    float x0 = floorf(fx), y0 = floorf(fy);
    float wx = fx - x0, wy = fy - y0;
    int xi = (int)x0, yi = (int)y0;
    const float* xp = x + (b * 128 + g * 32 + c) * HWHW;
    float v00 = 0.f, v10 = 0.f, v01 = 0.f, v11 = 0.f;
    bool okx0 = (xi >= 0) & (xi < 48), okx1 = (xi + 1 >= 0) & (xi + 1 < 48);
    if (yi >= 0 && yi < 48) {
      if (okx0) v00 = xp[yi * 48 + xi];
      if (okx1) v10 = xp[yi * 48 + xi + 1];
    }
    if (yi + 1 >= 0 && yi + 1 < 48) {
      if (okx0) v01 = xp[(yi + 1) * 48 + xi];
      if (okx1) v11 = xp[(yi + 1) * 48 + xi + 1];
    }
    kvs[c][j] = v00 * (1.f - wx) * (1.f - wy) + v10 * wx * (1.f - wy)
              + v01 * (1.f - wx) * wy + v11 * wx * wy;
  }
  __syncthreads();
  {
    int j = t >> 5, d = t & 31;
    float ak = 0.f, av = 0.f;
#pragma unroll
    for (int c = 0; c < 32; ++c) {
      float val = kvs[c][j];
      ak += wkl[d][c] * val;
      av += wvl[d][c] * val;
    }
    int jg = hd * 12 + j;
    ktb[bg * 4608 + jg * 32 + d] = f2bf(ak);
    vtb[bg * 5120 + d * 160 + jg] = f2bf(av);
  }
  if (hd == 0) {   // zero the v K-pad for this bg (j = 144..159)
    for (int u = t; u < 512; u += 384)
      vtb[bg * 5120 + (u >> 4) * 160 + 144 + (u & 15)] = 0;
  }
}

// Fused attention: block = (bg, 16 q-rows), 256 thr = 4 waves.
// q computed inline via MFMA from x/wq (C->A relayout through 1KB LDS);
// k/v operands straight from global; v-frags prefetched before P2.
__global__ __launch_bounds__(256) void attn_fused_kernel(
    const float* __restrict__ x, const float* __restrict__ wq,
    const ushort* __restrict__ ktb, const ushort* __restrict__ vtb,
    const float* __restrict__ vn0, const float* __restrict__ vn1,
    const float* __restrict__ w0, const float* __restrict__ b0,
    const float* __restrict__ w1, const float* __restrict__ b1,
    const float* __restrict__ w2, const float* __restrict__ b2,
    ushort* __restrict__ outh) {
  __shared__ __align__(16) char smem[11648];
  float* Ls = (float*)smem;                    // [16][LSP] fp32; P bf16 at dwords 64..143
  ushort* qbf = (ushort*)(smem + 9472);        // [16][32] bf16
  float* sv0 = (float*)(smem + 10496);         // [144]
  float* sv1 = (float*)(smem + 11072);         // [144]

  int bg = blockIdx.y, b = bg >> 2, g = bg & 3;
  int i0 = blockIdx.x * 16;
  int t = threadIdx.x;
  int w = t >> 6, lane = t & 63;
  int lam = lane & 15, quad = lane >> 4;

  if (t < JD) { sv0[t] = vn0[bg * JD + t]; sv1[t] = vn1[bg * JD + t]; }

  // ---- q-tile via MFMA: D = X[16 rows][32c] · Wq^T -> C-layout -> LDS ----
  {
    const float* wqg = wq + (g * 32) * 32;
    float4 wa = *(const float4*)(wqg + lam * 32 + quad * 8);
    float4 wb = *(const float4*)(wqg + lam * 32 + quad * 8 + 4);
    float4 wc = *(const float4*)(wqg + (16 + lam) * 32 + quad * 8);
    float4 wd = *(const float4*)(wqg + (16 + lam) * 32 + quad * 8 + 4);
    union { uint u[4]; short8 s8; } bf0, bf1, xa;
    bf0.u[0] = packbf(wa.y, wa.x); bf0.u[1] = packbf(wa.w, wa.z);
    bf0.u[2] = packbf(wb.y, wb.x); bf0.u[3] = packbf(wb.w, wb.z);
    bf1.u[0] = packbf(wc.y, wc.x); bf1.u[1] = packbf(wc.w, wc.z);
    bf1.u[2] = packbf(wd.y, wd.x); bf1.u[3] = packbf(wd.w, wd.z);
    const float* xg = x + (b * 128 + g * 32) * HWHW + i0;
#pragma unroll
    for (int j = 0; j < 4; ++j) {
      float x0 = xg[(quad * 8 + 2 * j) * HWHW + lam];
      float x1 = xg[(quad * 8 + 2 * j + 1) * HWHW + lam];
      xa.u[j] = packbf(x1, x0);
    }
    f32x4 z = {0.f, 0.f, 0.f, 0.f};
    f32x4 d0 = __builtin_amdgcn_mfma_f32_16x16x32_bf16(xa.s8, bf0.s8, z, 0, 0, 0);
    f32x4 d1 = __builtin_amdgcn_mfma_f32_16x16x32_bf16(xa.s8, bf1.s8, z, 0, 0, 0);
#pragma unroll
    for (int r = 0; r < 4; ++r) {
      qbf[(quad * 4 + r) * 32 + lam] = f2bf(d0[r]);
      qbf[(quad * 4 + r) * 32 + 16 + lam] = f2bf(d1[r]);
    }
  }

  // ---- per-lane resident weights ----
  float w00r[8], w01r[8], b0r[8];
#pragma unroll
  for (int j = 0; j < 8; ++j) {
    int k = quad * 8 + j;
    w00r[j] = w0[k]; w01r[j] = w0[32 + k]; b0r[j] = b0[k];
  }
  short8 w1f0, w1f1;   // W1^T A-frags (m=n-out, k=c-in), two 16-row tiles
#pragma unroll
  for (int j = 0; j < 8; ++j) {
    int k = quad * 8 + j;
    w1f0[j] = (short)f2bf(w1[k * 32 + lam]);
    w1f1[j] = (short)f2bf(w1[k * 32 + 16 + lam]);
  }
  f32x4 zA, zB;       // b1 folded into C-init (n = quad*4+r / 16+quad*4+r)
  float w2r[8];
#pragma unroll
  for (int r = 0; r < 4; ++r) {
    zA[r] = b1[quad * 4 + r];
    zB[r] = b1[16 + quad * 4 + r];
    w2r[r] = w2[quad * 4 + r];
    w2r[4 + r] = w2[16 + quad * 4 + r];
  }
  float b2s = b2[0];

  // ---- prefetch v-frags for P4 (waves 0,1) ----
  short8 vf[5];
  if (w < 2) {
    const ushort* vb = vtb + bg * 5120 + (w * 16 + lam) * 160;
#pragma unroll
    for (int kb = 0; kb < 5; ++kb)
      vf[kb] = *(const short8*)(vb + kb * 32 + quad * 8);
  }

  __syncthreads();   // B0: qbf + sv ready

  // ---- P1: sim = q·kT (scaled); k straight from global ----
  const float scale = 0.17677669529663687f;   // 32^-0.5
  {
    short8 aq = *(const short8*)(qbf + lam * 32 + quad * 8);
    const ushort* kb = ktb + bg * 4608;
#pragma unroll 1
    for (int jt = w; jt < 9; jt += 4) {
      short8 bk = *(const short8*)(kb + (jt * 16 + lam) * 32 + quad * 8);
      f32x4 acc = {0.f, 0.f, 0.f, 0.f};
      acc = __builtin_amdgcn_mfma_f32_16x16x32_bf16(aq, bk, acc, 0, 0, 0);
#pragma unroll
      for (int r = 0; r < 4; ++r)
        Ls[(quad * 4 + r) * LSP + jt * 16 + lam] = acc[r] * scale;
    }
  }
  __syncthreads();   // B2

  // ---- P2: CPB bias; wave owns 4 rows => 9 sub-iters of 64 pairs ----
#pragma unroll 1
  for (int s = 0; s < 9; ++s) {
    int P = s * 64 + lane;
    int ii = P / 144, jj = P - ii * 144;
    int ig = i0 + w * 4 + ii;
    int iy = ig / 48, ix = ig - iy * 48;
    float p0 = (float)ix * (2.f / 47.f) - 1.f - sv0[jj];
    float p1 = (float)iy * (2.f / 47.f) - 1.f - sv1[jj];
    float s0f = copysignf(__logf(1.f + fabsf(p0)), p0);
    float s1f = copysignf(__logf(1.f + fabsf(p1)), p1);
    float bm[4];
#pragma unroll
    for (int mt = 0; mt < 4; ++mt) {
      float s0 = __shfl(s0f, mt * 16 + lam, 64);
      float s1 = __shfl(s1f, mt * 16 + lam, 64);
      float h[8];
#pragma unroll
      for (int j = 0; j < 8; ++j)
        h[j] = fmaxf(fmaf(s0, w00r[j], fmaf(s1, w01r[j], b0r[j])), 0.f);
      union { uint u[4]; short8 s8; } cvt;   // truncating f32->bf16 pack
#pragma unroll
      for (int j = 0; j < 4; ++j) cvt.u[j] = packbf(h[2 * j + 1], h[2 * j]);
      f32x4 dA = __builtin_amdgcn_mfma_f32_16x16x32_bf16(w1f0, cvt.s8, zA, 0, 0, 0);
      f32x4 dB = __builtin_amdgcn_mfma_f32_16x16x32_bf16(w1f1, cvt.s8, zB, 0, 0, 0);
      float acc = 0.f;
#pragma unroll
      for (int r = 0; r < 4; ++r) {
        acc = fmaf(fmaxf(dA[r], 0.f), w2r[r], acc);
        acc = fmaf(fmaxf(dB[r], 0.f), w2r[4 + r], acc);
      }
      acc += __shfl_xor(acc, 16, 64);
      acc += __shfl_xor(acc, 32, 64);
      bm[mt] = acc;
    }
    float biasv = (quad == 0 ? bm[0] : quad == 1 ? bm[1] : quad == 2 ? bm[2] : bm[3]) + b2s;
    Ls[(w * 4 + ii) * LSP + jj] += biasv;
  }
  __syncthreads();   // B3

  // ---- P3: softmax per row (wave owns 4 rows); P packed bf16 in-place ----
#pragma unroll 1
  for (int rr = 0; rr < 4; ++rr) {
    int row = w * 4 + rr;
    const float* Lp = Ls + row * LSP;
    float l0 = Lp[lane], l1 = Lp[64 + lane];
    float l2 = (lane < 16) ? Lp[128 + lane] : -INFINITY;
    float m = fmaxf(fmaxf(l0, l1), l2);
#pragma unroll
    for (int k = 32; k >= 1; k >>= 1) m = fmaxf(m, __shfl_xor(m, k, 64));
    float e0 = __expf(l0 - m), e1 = __expf(l1 - m);
    float e2 = (lane < 16) ? __expf(l2 - m) : 0.f;
    float sum = e0 + e1 + e2;
#pragma unroll
    for (int k = 32; k >= 1; k >>= 1) sum += __shfl_xor(sum, k, 64);
    float inv = 1.f / sum;
    ushort* pb = (ushort*)(Lp + 64);
    pb[lane] = f2bf(e0 * inv);
    pb[64 + lane] = f2bf(e1 * inv);
    if (lane < 32) pb[128 + lane] = (lane < 16) ? f2bf(e2 * inv) : (ushort)0;
  }
  __syncthreads();   // B4

  // ---- P4: O = P·v (K=160, zero-padded); waves 0,1 take the 2 col-halves ----
  if (w < 2) {
    f32x4 o = {0.f, 0.f, 0.f, 0.f};
    const ushort* pb = (const ushort*)(Ls + lam * LSP + 64);
#pragma unroll
    for (int kb = 0; kb < 5; ++kb) {
      short8 ap = *(const short8*)(pb + kb * 32 + quad * 8);
      o = __builtin_amdgcn_mfma_f32_16x16x32_bf16(ap, vf[kb], o, 0, 0, 0);
    }
#pragma unroll
    for (int r = 0; r < 4; ++r) {
      int ig = i0 + quad * 4 + r;
      outh[((long)b * HWHW + ig) * 128 + g * 32 + w * 16 + lam] = f2bf(o[r]);
    }
  }
}

// grid (144 hw-chunks, 2 b), 256 thr = 4 waves. MFMA out-proj, zero LDS:
// A-frags straight from bf16 outh; B-frags from fp32 wo with inline v_perm pack.
__global__ __launch_bounds__(256) void out_kernel(
    const ushort* __restrict__ outh, const float* __restrict__ wo,
    const float* __restrict__ bo, const float* __restrict__ x,
    const float* __restrict__ gamma, float* __restrict__ out) {
  int b = blockIdx.y;
  int hw0 = blockIdx.x * 16;
  int t = threadIdx.x;
  int w = t >> 6, lane = t & 63, lam = lane & 15, quad = lane >> 4;
  const ushort* abase = outh + ((long)b * HWHW + hw0 + lam) * 128 + quad * 8;
  const float* wb0 = wo + (w * 32 + lam) * 128 + quad * 8;
  const float* wb1 = wo + (w * 32 + 16 + lam) * 128 + quad * 8;
  f32x4 acc0 = {0.f, 0.f, 0.f, 0.f}, acc1 = {0.f, 0.f, 0.f, 0.f};
#pragma unroll
  for (int ks = 0; ks < 4; ++ks) {
    short8 a = *(const short8*)(abase + ks * 32);
    float4 wa = *(const float4*)(wb0 + ks * 32);
    float4 wb = *(const float4*)(wb0 + ks * 32 + 4);
    float4 wc = *(const float4*)(wb1 + ks * 32);
    float4 wd = *(const float4*)(wb1 + ks * 32 + 4);
    union { uint u[4]; short8 s8; } p0, p1;
    p0.u[0] = packbf(wa.y, wa.x); p0.u[1] = packbf(wa.w, wa.z);
    p0.u[2] = packbf(wb.y, wb.x); p0.u[3] = packbf(wb.w, wb.z);
    p1.u[0] = packbf(wc.y, wc.x); p1.u[1] = packbf(wc.w, wc.z);
    p1.u[2] = packbf(wd.y, wd.x); p1.u[3] = packbf(wd.w, wd.z);
    acc0 = __builtin_amdgcn_mfma_f32_16x16x32_bf16(a, p0.s8, acc0, 0, 0, 0);
    acc1 = __builtin_amdgcn_mfma_f32_16x16x32_bf16(a, p1.s8, acc1, 0, 0, 0);
  }
  float gm = gamma[0];
  float* out0 = out;
  float* out1 = out + 2 * 128 * HWHW;
#pragma unroll
  for (int nt = 0; nt < 2; ++nt) {
    f32x4 acc = nt ? acc1 : acc0;
    int oc = w * 32 + nt * 16 + lam;
    float bv = bo[oc];
    long base = ((long)(b * 128 + oc)) * HWHW + hw0 + quad * 4;
    float4 xv = *(const float4*)(x + base);
    float4 a1, a0;
    a1.x = acc[0] + bv; a1.y = acc[1] + bv; a1.z = acc[2] + bv; a1.w = acc[3] + bv;
    a0.x = fmaf(gm, a1.x, xv.x); a0.y = fmaf(gm, a1.y, xv.y);
    a0.z = fmaf(gm, a1.z, xv.z); a0.w = fmaf(gm, a1.w, xv.w);
    *(float4*)(out1 + base) = a1;
    *(float4*)(out0 + base) = a0;
  }
}

extern "C" void kernel_launch(void* const* d_in, const int* in_sizes, int n_in,
                              void* d_out, int out_size, void* d_ws, size_t ws_size,
                              hipStream_t stream) {
  const float* x     = (const float*)d_in[0];
  const float* gamma = (const float*)d_in[1];
  const float* wq    = (const float*)d_in[2];
  const float* wk    = (const float*)d_in[3];
  const float* wv    = (const float*)d_in[4];
  const float* wo    = (const float*)d_in[5];
  const float* bo    = (const float*)d_in[6];
  const float* wdw   = (const float*)d_in[7];
  const float* bdw   = (const float*)d_in[8];
  const float* wproj = (const float*)d_in[9];
  const float* cw0   = (const float*)d_in[10];
  const float* cb0   = (const float*)d_in[11];
  const float* cw1   = (const float*)d_in[12];
  const float* cb1   = (const float*)d_in[13];
  const float* cw2   = (const float*)d_in[14];
  const float* cb2   = (const float*)d_in[15];
  char* wsb = (char*)d_ws;
  float* vn0  = (float*)wsb;
  float* vn1  = (float*)(wsb + 4608);
  ushort* ktb = (ushort*)(wsb + 9216);
  ushort* vtb = (ushort*)(wsb + 82944);
  ushort* outh = (ushort*)(wsb + 164864);
  float* out  = (float*)d_out;

  offset_kv_kernel<<<dim3(12, 8), 384, 0, stream>>>(x, wq, wdw, bdw, wproj, wk, wv,
                                                    vn0, vn1, ktb, vtb);
  attn_fused_kernel<<<dim3(144, 8), 256, 0, stream>>>(x, wq, ktb, vtb, vn0, vn1,
                                                      cw0, cb0, cw1, cb1, cw2, cb2, outh);
  out_kernel<<<dim3(144, 2), 256, 0, stream>>>(outh, wo, bo, x, gamma, out);
}